// Round 6
// baseline (426.127 us; speedup 1.0000x reference)
//
#include <hip/hip_runtime.h>

// Swin cross-attention pipeline v6 for MI355X.
// v5 -> v6: proj split to one-GEMM-per-block (grid 680x{K,V,Q} interleaved),
// 36.9KB union LDS tile -> 4 blocks/CU (16 waves/CU, 2x in-flight loads vs
// v5's merged 2-block/CU version). Uniform per-block work, no tail imbalance.
// attnop (attention + Wo fused, O stays in LDS) unchanged from v5.

using bf16x8 = __attribute__((ext_vector_type(8))) __bf16;
using f32x4  = __attribute__((ext_vector_type(4))) float;
using u16x4  = __attribute__((ext_vector_type(4))) unsigned short;
using u16x8  = __attribute__((ext_vector_type(8))) unsigned short;

__device__ __forceinline__ unsigned short f2bf(float f){
  unsigned int x = __float_as_uint(f);
  x += 0x7FFFu + ((x >> 16) & 1u);          // RNE
  return (unsigned short)(x >> 16);
}
__device__ __forceinline__ float bf2f(unsigned short u){
  return __uint_as_float((unsigned int)u << 16);
}
__device__ __forceinline__ void store_bf4(unsigned short* dst, f32x4 v){
  u16x4 o;
  o[0]=f2bf(v[0]); o[1]=f2bf(v[1]); o[2]=f2bf(v[2]); o[3]=f2bf(v[3]);
  *reinterpret_cast<u16x4*>(dst) = o;
}

#define MFMA16 __builtin_amdgcn_mfma_f32_16x16x32_bf16

__global__ void wcvt_kernel(const float* __restrict__ w1,
                            const float* __restrict__ w2,
                            unsigned short* __restrict__ dst){
  int i = blockIdx.x * 256 + threadIdx.x;
  const float4* src = (i < 262144) ? (reinterpret_cast<const float4*>(w1) + i)
                                   : (reinterpret_cast<const float4*>(w2) + (i - 262144));
  float4 v = *src;
  u16x4 o; o[0]=f2bf(v.x); o[1]=f2bf(v.y); o[2]=f2bf(v.z); o[3]=f2bf(v.w);
  reinterpret_cast<u16x4*>(dst)[i] = o;
}

// ---- transpose fp32 [C,HW] -> bf16 Ft[token][c] -----------------------------
__global__ __launch_bounds__(256, 2) void xpose_kernel(
    const float* __restrict__ g0, const float* __restrict__ g1,
    const float* __restrict__ g2, const float* __restrict__ g3,
    unsigned short* __restrict__ Ft)
{
  __shared__ float T[64][65];
  int bid = blockIdx.x;
  int r; const float* feat; int Hl; size_t tbase;
  if (bid < 4096){ r = bid;        feat = g0; Hl = 128; tbase = 0; }
  else if (bid < 5120){ r = bid - 4096; feat = g1; Hl = 64;  tbase = 65536; }
  else if (bid < 5376){ r = bid - 5120; feat = g2; Hl = 32;  tbase = 81920; }
  else { r = bid - 5376; feat = g3; Hl = 16;  tbase = 86016; }
  size_t HW = (size_t)Hl * Hl;
  int hw64 = (int)(HW >> 6);
  int bat = r / (4 * hw64);
  int r2 = r - bat * 4 * hw64;
  int ct = r2 / hw64, hwt = r2 - ct * hw64;

  const float* src = feat + (size_t)bat * HW * 256 + (size_t)(ct * 64) * HW + (size_t)hwt * 64;
  int tid = threadIdx.x;
  int cq = tid >> 4, hw0 = (tid & 15) * 4;
  #pragma unroll
  for (int p = 0; p < 4; ++p){
    int c = p * 16 + cq;
    const float* sp = src + (size_t)c * HW + hw0;
    float4 v = *reinterpret_cast<const float4*>(sp);
    T[c][hw0] = v.x; T[c][hw0+1] = v.y; T[c][hw0+2] = v.z; T[c][hw0+3] = v.w;
  }
  __syncthreads();
  unsigned short* dst = Ft + (tbase + (size_t)bat * HW + (size_t)hwt * 64) * 256 + ct * 64;
  #pragma unroll
  for (int p = 0; p < 2; ++p){
    int id = p * 256 + tid;
    int t = id >> 3, c0 = (id & 7) * 8;
    u16x8 o;
    #pragma unroll
    for (int j = 0; j < 8; ++j) o[j] = f2bf(T[c0 + j][t]);
    *reinterpret_cast<u16x8*>(dst + (size_t)t * 256 + c0) = o;
  }
}

// ---- transpose back: Gt[token][c] bf16 -> fp32 out [C,HW], ALL 4 batches ----
__global__ __launch_bounds__(256, 2) void untrans_kernel(
    const unsigned short* __restrict__ Gt, float* __restrict__ outb)
{
  __shared__ float T[64][65];
  int bid = blockIdx.x;
  int r; int Hl; size_t tbase, ooff;
  if (bid < 4096){ r = bid;        Hl = 128; tbase = 0;     ooff = 0; }
  else if (bid < 5120){ r = bid - 4096; Hl = 64; tbase = 65536; ooff = 16777216; }
  else if (bid < 5376){ r = bid - 5120; Hl = 32; tbase = 81920; ooff = 20971520; }
  else { r = bid - 5376; Hl = 16; tbase = 86016; ooff = 22020096; }
  size_t HW = (size_t)Hl * Hl;
  int hw64 = (int)(HW >> 6);
  int bat = r / (4 * hw64);
  int r2 = r - bat * 4 * hw64;
  int ct = r2 / hw64, hwt = r2 - ct * hw64;

  const unsigned short* src = Gt + (tbase + (size_t)bat * HW + (size_t)hwt * 64) * 256 + ct * 64;
  int tid = threadIdx.x;
  #pragma unroll
  for (int p = 0; p < 2; ++p){
    int id = p * 256 + tid;
    int t = id >> 3, c0 = (id & 7) * 8;
    u16x8 v = *reinterpret_cast<const u16x8*>(src + (size_t)t * 256 + c0);
    #pragma unroll
    for (int j = 0; j < 8; ++j) T[t][c0 + j] = bf2f(v[j]);
  }
  __syncthreads();
  float* dst = outb + ooff + (size_t)bat * HW * 256 + (size_t)(ct * 64) * HW + (size_t)hwt * 64;
  int cq = tid >> 4, hw0 = (tid & 15) * 4;
  #pragma unroll
  for (int p = 0; p < 4; ++p){
    int c = p * 16 + cq;
    float4 v;
    v.x = T[hw0][c]; v.y = T[hw0+1][c]; v.z = T[hw0+2][c]; v.w = T[hw0+3][c];
    *reinterpret_cast<float4*>(dst + (size_t)c * HW + hw0) = v;
  }
}

// ---- window geometry --------------------------------------------------------
struct WinGeo { int H, W, b, lvl; size_t HW, winoff, tbase, ooff; };

__device__ __forceinline__ WinGeo decode_win(int win){
  WinGeo g; int wloc;
  if (win < 512){ g.lvl = 0; wloc = win;      g.H = 128; g.tbase = 0;     g.ooff = 0; }
  else if (win < 640){ g.lvl = 1; wloc = win - 512; g.H = 64; g.tbase = 65536; g.ooff = 16777216; }
  else if (win < 672){ g.lvl = 2; wloc = win - 640; g.H = 32; g.tbase = 81920; g.ooff = 20971520; }
  else { g.lvl = 3; wloc = win - 672; g.H = 16; g.tbase = 86016; g.ooff = 22020096; }
  g.W = g.H; g.HW = (size_t)g.H * g.W;
  int nww = g.H >> 3, npb = nww * nww;
  g.b = wloc / npb;
  int r = wloc - g.b * npb;
  int wh = r / nww, ww = r - wh * nww;
  g.winoff = (size_t)(wh * 8) * g.W + (size_t)(ww * 8);
  return g;
}

// coalesced flush: LDS [64][264] tile -> global [64][256] bf16 rows
__device__ __forceinline__ void flush_tile_td(const unsigned short* __restrict__ st,
    unsigned short* __restrict__ dst, int tid){
  #pragma unroll
  for (int p = 0; p < 8; ++p){
    int id = p * 256 + tid;
    int t = id >> 5, c = (id & 31) * 8;
    *reinterpret_cast<u16x8*>(dst + (size_t)t * 256 + c) =
      *reinterpret_cast<const u16x8*>(st + t * 264 + c);
  }
}
// coalesced flush: LDS [256][72] tile -> global [256][64] bf16 rows
__device__ __forceinline__ void flush_tile_vt(const unsigned short* __restrict__ st,
    unsigned short* __restrict__ dst, int tid){
  #pragma unroll
  for (int p = 0; p < 8; ++p){
    int id = p * 256 + tid;
    int d = id >> 3, u = (id & 7) * 8;
    *reinterpret_cast<u16x8*>(dst + (size_t)d * 64 + u) =
      *reinterpret_cast<const u16x8*>(st + d * 72 + u);
  }
}

// ---- P1: one GEMM per block. bid = win*3 + {0:K, 1:V, 2:Q} ------------------
__global__ __launch_bounds__(256, 4) void proj_kernel(
    const unsigned short* __restrict__ Ft, const unsigned short* __restrict__ Gt,
    const unsigned short* __restrict__ wball,
    unsigned short* __restrict__ Qb, unsigned short* __restrict__ Kb,
    unsigned short* __restrict__ VTb, int phase)
{
  __shared__ alignas(16) unsigned short ST[256*72];   // 36864 B union tile
  int bid = blockIdx.x;
  int win = bid / 3, ty = bid - win * 3;   // 0=K, 1=V, 2=Q
  WinGeo g = decode_win(win);
  int tid = threadIdx.x;
  int w = tid >> 6, l = tid & 63, l15 = l & 15, l4 = l >> 4, wd = w * 64;

  // token source: Q reads X (bat depends on phase); K/V read Y
  const unsigned short* S;
  if (ty == 2){
    int batx = (phase == 0) ? g.b : g.b + 2;
    S = Ft + (g.tbase + (size_t)batx * g.HW) * 256;
  } else {
    S = (phase == 0) ? Ft + (g.tbase + (size_t)(g.b + 2) * g.HW) * 256
                     : Gt + (g.tbase + (size_t)g.b * g.HW) * 256;
  }
  size_t rowo[4];
  #pragma unroll
  for (int ni = 0; ni < 4; ++ni){
    int t = ni * 16 + l15;
    rowo[ni] = ((size_t)g.winoff + (size_t)(t >> 3) * g.W + (t & 7)) * 256;
  }
  const unsigned short* Wbase = wball + ((size_t)(phase * 16 + g.lvl * 4) << 16);
  const unsigned short* Wm = (ty == 0) ? Wbase + 65536
                           : (ty == 1) ? Wbase + 131072 : Wbase;
  size_t woff = (size_t)win << 14;

  f32x4 acc[4][4];
  #pragma unroll
  for (int i = 0; i < 4; ++i)
    #pragma unroll
    for (int j = 0; j < 4; ++j) acc[i][j] = f32x4{0.f,0.f,0.f,0.f};

  #pragma unroll
  for (int ks = 0; ks < 8; ++ks){
    int k0 = ks * 32 + l4 * 8;
    bf16x8 tf[4], wf[4];
    #pragma unroll
    for (int i = 0; i < 4; ++i){
      tf[i] = *reinterpret_cast<const bf16x8*>(S + rowo[i] + k0);
      wf[i] = *reinterpret_cast<const bf16x8*>(Wm + (size_t)((wd + i*16 + l15) * 256 + k0));
    }
    __builtin_amdgcn_s_setprio(1);
    if (ty == 1){
      #pragma unroll
      for (int mi = 0; mi < 4; ++mi)
        #pragma unroll
        for (int ni = 0; ni < 4; ++ni)
          acc[mi][ni] = MFMA16(tf[mi], wf[ni], acc[mi][ni], 0, 0, 0);
    } else {
      #pragma unroll
      for (int mi = 0; mi < 4; ++mi)
        #pragma unroll
        for (int ni = 0; ni < 4; ++ni)
          acc[mi][ni] = MFMA16(wf[mi], tf[ni], acc[mi][ni], 0, 0, 0);
    }
    __builtin_amdgcn_s_setprio(0);
  }

  if (ty == 1){
    // V^T [d][u]
    #pragma unroll
    for (int mi = 0; mi < 4; ++mi){
      int u0 = mi*16 + l4*4;
      #pragma unroll
      for (int ni = 0; ni < 4; ++ni)
        store_bf4(&ST[(wd + ni*16 + l15) * 72 + u0], acc[mi][ni]);
    }
    __syncthreads();
    flush_tile_vt(ST, VTb + woff, tid);
  } else {
    // K or Q: [t][d]
    #pragma unroll
    for (int mi = 0; mi < 4; ++mi){
      int d0 = wd + mi*16 + l4*4;
      #pragma unroll
      for (int ni = 0; ni < 4; ++ni)
        store_bf4(&ST[(ni*16 + l15) * 264 + d0], acc[mi][ni]);
    }
    __syncthreads();
    flush_tile_td(ST, ((ty == 0) ? Kb : Qb) + woff, tid);
  }
}

// ---- P2: attention + output projection fused per window ---------------------
__global__ __launch_bounds__(256, 3) void attnop_kernel(
    const unsigned short* __restrict__ Qb, const unsigned short* __restrict__ Kb,
    const unsigned short* __restrict__ VTb, const unsigned short* __restrict__ Ft,
    const unsigned short* __restrict__ wball,
    unsigned short* __restrict__ Gt, int phase)
{
  __shared__ alignas(16) unsigned short UB[64*264];   // P -> O -> out tile
  int win = blockIdx.x;
  WinGeo g = decode_win(win);
  size_t woff = (size_t)win << 14;
  const unsigned short* Qw = Qb + woff;
  const unsigned short* Kw = Kb + woff;
  const unsigned short* VTw = VTb + woff;

  int tid = threadIdx.x;
  int w = tid >> 6, l = tid & 63, l15 = l & 15, l4 = l >> 4, wd = w * 64;
  int h = w >> 1, tc = w & 1;

  int bat = (phase == 0) ? g.b : g.b + 2;
  const unsigned short* Xres = Ft + (g.tbase + (size_t)bat * g.HW) * 256;
  unsigned short* Gout = Gt + (g.tbase + (size_t)bat * g.HW) * 256;
  const unsigned short* Wo = wball + ((size_t)(phase * 16 + g.lvl * 4 + 3) << 16);

  // ---- S^T[u][t] per head ----
  f32x4 s[4][2];
  #pragma unroll
  for (int i = 0; i < 4; ++i){ s[i][0] = f32x4{0.f,0.f,0.f,0.f}; s[i][1] = f32x4{0.f,0.f,0.f,0.f}; }
  #pragma unroll
  for (int ks = 0; ks < 4; ++ks){
    int k0 = h * 128 + ks * 32 + l4 * 8;
    bf16x8 a[4], bb[2];
    #pragma unroll
    for (int mi = 0; mi < 4; ++mi)
      a[mi] = *reinterpret_cast<const bf16x8*>(Kw + (size_t)(mi*16 + l15) * 256 + k0);
    #pragma unroll
    for (int ni = 0; ni < 2; ++ni)
      bb[ni] = *reinterpret_cast<const bf16x8*>(Qw + (size_t)(tc*32 + ni*16 + l15) * 256 + k0);
    __builtin_amdgcn_s_setprio(1);
    #pragma unroll
    for (int mi = 0; mi < 4; ++mi)
      #pragma unroll
      for (int ni = 0; ni < 2; ++ni)
        s[mi][ni] = MFMA16(a[mi], bb[ni], s[mi][ni], 0, 0, 0);
    __builtin_amdgcn_s_setprio(0);
  }

  // ---- softmax over u (per column t), P -> LDS bf16 ----
  const float SCL = 0.08838834764831845f;   // 1/sqrt(128)
  #pragma unroll
  for (int ni = 0; ni < 2; ++ni){
    float m = s[0][ni][0];
    #pragma unroll
    for (int mi = 0; mi < 4; ++mi)
      #pragma unroll
      for (int reg = 0; reg < 4; ++reg) m = fmaxf(m, s[mi][ni][reg]);
    m = fmaxf(m, __shfl_xor(m, 16));
    m = fmaxf(m, __shfl_xor(m, 32));
    float sum = 0.f;
    #pragma unroll
    for (int mi = 0; mi < 4; ++mi)
      #pragma unroll
      for (int reg = 0; reg < 4; ++reg){
        float e = __expf((s[mi][ni][reg] - m) * SCL);
        s[mi][ni][reg] = e; sum += e;
      }
    sum += __shfl_xor(sum, 16);
    sum += __shfl_xor(sum, 32);
    float rs = 1.0f / sum;
    int t = tc*32 + ni*16 + l15;
    #pragma unroll
    for (int mi = 0; mi < 4; ++mi){
      f32x4 pv;
      #pragma unroll
      for (int reg = 0; reg < 4; ++reg) pv[reg] = s[mi][ni][reg] * rs;
      store_bf4(&UB[h * 4608 + t * 72 + mi*16 + l4*4], pv);
    }
  }
  __syncthreads();

  // ---- O^T[c][t] = V^T * P^T ----
  f32x4 acc[4][4];
  #pragma unroll
  for (int i = 0; i < 4; ++i)
    #pragma unroll
    for (int j = 0; j < 4; ++j) acc[i][j] = f32x4{0.f,0.f,0.f,0.f};
  #pragma unroll
  for (int ks = 0; ks < 2; ++ks){
    int k0 = ks * 32 + l4 * 8;
    bf16x8 a[4], bb[4];
    #pragma unroll
    for (int mi = 0; mi < 4; ++mi)
      a[mi] = *reinterpret_cast<const bf16x8*>(VTw + (size_t)(wd + mi*16 + l15) * 64 + k0);
    #pragma unroll
    for (int ni = 0; ni < 4; ++ni)
      bb[ni] = *reinterpret_cast<const bf16x8*>(&UB[h * 4608 + (ni*16 + l15) * 72 + k0]);
    __builtin_amdgcn_s_setprio(1);
    #pragma unroll
    for (int mi = 0; mi < 4; ++mi)
      #pragma unroll
      for (int ni = 0; ni < 4; ++ni)
        acc[mi][ni] = MFMA16(a[mi], bb[ni], acc[mi][ni], 0, 0, 0);
    __builtin_amdgcn_s_setprio(0);
  }
  __syncthreads();   // all P reads done; O tile may overwrite UB
  #pragma unroll
  for (int mi = 0; mi < 4; ++mi){
    int c0 = wd + mi*16 + l4*4;
    #pragma unroll
    for (int ni = 0; ni < 4; ++ni)
      store_bf4(&UB[(ni*16 + l15) * 264 + c0], acc[mi][ni]);
  }
  __syncthreads();

  // ---- out^T = Wo * o^T (O fragments from LDS) ----
  #pragma unroll
  for (int i = 0; i < 4; ++i)
    #pragma unroll
    for (int j = 0; j < 4; ++j) acc[i][j] = f32x4{0.f,0.f,0.f,0.f};
  #pragma unroll
  for (int ks = 0; ks < 8; ++ks){
    int k0 = ks * 32 + l4 * 8;
    bf16x8 a[4], bb[4];
    #pragma unroll
    for (int mi = 0; mi < 4; ++mi)
      a[mi] = *reinterpret_cast<const bf16x8*>(Wo + (size_t)((wd + mi*16 + l15) * 256 + k0));
    #pragma unroll
    for (int ni = 0; ni < 4; ++ni)
      bb[ni] = *reinterpret_cast<const bf16x8*>(&UB[(ni*16 + l15) * 264 + k0]);
    __builtin_amdgcn_s_setprio(1);
    #pragma unroll
    for (int mi = 0; mi < 4; ++mi)
      #pragma unroll
      for (int ni = 0; ni < 4; ++ni)
        acc[mi][ni] = MFMA16(a[mi], bb[ni], acc[mi][ni], 0, 0, 0);
    __builtin_amdgcn_s_setprio(0);
  }
  __syncthreads();   // all O reads done; out tile may overwrite UB
  #pragma unroll
  for (int mi = 0; mi < 4; ++mi){
    int c0 = wd + mi*16 + l4*4;
    #pragma unroll
    for (int ni = 0; ni < 4; ++ni)
      store_bf4(&UB[(ni*16 + l15) * 264 + c0], acc[mi][ni]);
  }
  __syncthreads();

  // ---- fused flush: out + residual, relu, 16B coalesced -> Gt ----
  #pragma unroll
  for (int p = 0; p < 8; ++p){
    int id = p * 256 + tid;
    int t = id >> 5, c = (id & 31) * 8;
    size_t ro = ((size_t)g.winoff + (size_t)(t >> 3) * g.W + (t & 7)) * 256 + c;
    u16x8 ov = *reinterpret_cast<const u16x8*>(&UB[t * 264 + c]);
    u16x8 rv = *reinterpret_cast<const u16x8*>(Xres + ro);
    u16x8 o;
    #pragma unroll
    for (int j = 0; j < 8; ++j)
      o[j] = f2bf(fmaxf(bf2f(ov[j]) + bf2f(rv[j]), 0.f));
    *reinterpret_cast<u16x8*>(Gout + ro) = o;
  }
}

// ======================= round-1 fused fallback ==============================
__global__ __launch_bounds__(256, 1) void swin_phase(
    const float* __restrict__ g0, const float* __restrict__ g1,
    const float* __restrict__ g2, const float* __restrict__ g3,
    const unsigned short* __restrict__ wball,
    float* __restrict__ outb, int phase)
{
  __shared__ alignas(16) unsigned short R0[64*264];
  __shared__ alignas(16) unsigned short R1[64*264];
  __shared__ alignas(16) unsigned short R2[256*72];
  __shared__ alignas(16) unsigned short R3[64*264];

  int bid = blockIdx.x;
  WinGeo g = decode_win(bid);
  const float* feat = (g.lvl == 0) ? g0 : (g.lvl == 1) ? g1 : (g.lvl == 2) ? g2 : g3;
  size_t CHW = g.HW * 256;

  const float* xsrc; const float* ysrc; float* outp;
  if (phase == 0){
    xsrc = feat + (size_t)g.b * CHW + g.winoff;
    ysrc = feat + (size_t)(g.b + 2) * CHW + g.winoff;
    outp = outb + g.ooff + (size_t)g.b * CHW + g.winoff;
  } else {
    xsrc = feat + (size_t)(g.b + 2) * CHW + g.winoff;
    ysrc = outb + g.ooff + (size_t)g.b * CHW + g.winoff;
    outp = outb + g.ooff + (size_t)(g.b + 2) * CHW + g.winoff;
  }
  const unsigned short* Wq = wball + ((size_t)(phase * 16 + g.lvl * 4) << 16);
  const unsigned short* Wk = Wq + 65536;
  const unsigned short* Wv = Wq + 2 * 65536;
  const unsigned short* Wo = Wq + 3 * 65536;

  int tid = threadIdx.x;
  int w = tid >> 6, l = tid & 63, l15 = l & 15, l4 = l >> 4, wd = w * 64;
  int hi0 = l >> 3, wi0 = l & 7;

  {
    const float* p0 = ysrc + (size_t)hi0 * g.W + wi0;
    #pragma unroll
    for (int oc = 0; oc < 8; ++oc){
      int c0 = (oc * 4 + w) * 8;
      const float* p = p0 + (size_t)c0 * g.HW;
      u16x8 uv;
      #pragma unroll
      for (int j = 0; j < 8; ++j) uv[j] = f2bf(p[(size_t)j * g.HW]);
      *reinterpret_cast<u16x8*>(&R0[l * 264 + c0]) = uv;
    }
  }
  __syncthreads();
  {
    f32x4 acc[4][4];
    #pragma unroll
    for (int i = 0; i < 4; ++i)
      #pragma unroll
      for (int j = 0; j < 4; ++j) acc[i][j] = f32x4{0.f,0.f,0.f,0.f};
    #pragma unroll
    for (int ks = 0; ks < 8; ++ks){
      int k0 = ks * 32 + l4 * 8;
      bf16x8 a[4], bb[4];
      #pragma unroll
      for (int mi = 0; mi < 4; ++mi)
        a[mi] = *reinterpret_cast<const bf16x8*>(Wk + (size_t)((wd + mi*16 + l15) * 256 + k0));
      #pragma unroll
      for (int ni = 0; ni < 4; ++ni)
        bb[ni] = *reinterpret_cast<const bf16x8*>(&R0[(ni*16 + l15) * 264 + k0]);
      #pragma unroll
      for (int mi = 0; mi < 4; ++mi)
        #pragma unroll
        for (int ni = 0; ni < 4; ++ni)
          acc[mi][ni] = MFMA16(a[mi], bb[ni], acc[mi][ni], 0, 0, 0);
    }
    #pragma unroll
    for (int mi = 0; mi < 4; ++mi){
      int d0 = wd + mi*16 + l4*4;
      #pragma unroll
      for (int ni = 0; ni < 4; ++ni)
        store_bf4(&R1[(ni*16 + l15) * 264 + d0], acc[mi][ni]);
    }
  }
  {
    f32x4 acc[4][4];
    #pragma unroll
    for (int i = 0; i < 4; ++i)
      #pragma unroll
      for (int j = 0; j < 4; ++j) acc[i][j] = f32x4{0.f,0.f,0.f,0.f};
    #pragma unroll
    for (int ks = 0; ks < 8; ++ks){
      int k0 = ks * 32 + l4 * 8;
      bf16x8 a[4], bb[4];
      #pragma unroll
      for (int mi = 0; mi < 4; ++mi)
        a[mi] = *reinterpret_cast<const bf16x8*>(&R0[(mi*16 + l15) * 264 + k0]);
      #pragma unroll
      for (int ni = 0; ni < 4; ++ni)
        bb[ni] = *reinterpret_cast<const bf16x8*>(Wv + (size_t)((wd + ni*16 + l15) * 256 + k0));
      #pragma unroll
      for (int mi = 0; mi < 4; ++mi)
        #pragma unroll
        for (int ni = 0; ni < 4; ++ni)
          acc[mi][ni] = MFMA16(a[mi], bb[ni], acc[mi][ni], 0, 0, 0);
    }
    #pragma unroll
    for (int mi = 0; mi < 4; ++mi){
      int u0 = mi*16 + l4*4;
      #pragma unroll
      for (int ni = 0; ni < 4; ++ni)
        store_bf4(&R2[(wd + ni*16 + l15) * 72 + u0], acc[mi][ni]);
    }
  }
  __syncthreads();
  {
    const float* p0 = xsrc + (size_t)hi0 * g.W + wi0;
    #pragma unroll
    for (int oc = 0; oc < 8; ++oc){
      int c0 = (oc * 4 + w) * 8;
      const float* p = p0 + (size_t)c0 * g.HW;
      u16x8 uv;
      #pragma unroll
      for (int j = 0; j < 8; ++j) uv[j] = f2bf(p[(size_t)j * g.HW]);
      *reinterpret_cast<u16x8*>(&R0[l * 264 + c0]) = uv;
    }
  }
  __syncthreads();
  {
    f32x4 acc[4][4];
    #pragma unroll
    for (int i = 0; i < 4; ++i)
      #pragma unroll
      for (int j = 0; j < 4; ++j) acc[i][j] = f32x4{0.f,0.f,0.f,0.f};
    #pragma unroll
    for (int ks = 0; ks < 8; ++ks){
      int k0 = ks * 32 + l4 * 8;
      bf16x8 a[4], bb[4];
      #pragma unroll
      for (int mi = 0; mi < 4; ++mi)
        a[mi] = *reinterpret_cast<const bf16x8*>(Wq + (size_t)((wd + mi*16 + l15) * 256 + k0));
      #pragma unroll
      for (int ni = 0; ni < 4; ++ni)
        bb[ni] = *reinterpret_cast<const bf16x8*>(&R0[(ni*16 + l15) * 264 + k0]);
      #pragma unroll
      for (int mi = 0; mi < 4; ++mi)
        #pragma unroll
        for (int ni = 0; ni < 4; ++ni)
          acc[mi][ni] = MFMA16(a[mi], bb[ni], acc[mi][ni], 0, 0, 0);
    }
    #pragma unroll
    for (int mi = 0; mi < 4; ++mi){
      int d0 = wd + mi*16 + l4*4;
      #pragma unroll
      for (int ni = 0; ni < 4; ++ni)
        store_bf4(&R3[(ni*16 + l15) * 264 + d0], acc[mi][ni]);
    }
  }
  __syncthreads();

  int h = w >> 1, tc = w & 1;
  {
    f32x4 s[4][2];
    #pragma unroll
    for (int i = 0; i < 4; ++i){ s[i][0] = f32x4{0.f,0.f,0.f,0.f}; s[i][1] = f32x4{0.f,0.f,0.f,0.f}; }
    #pragma unroll
    for (int ks = 0; ks < 4; ++ks){
      int k0 = h * 128 + ks * 32 + l4 * 8;
      bf16x8 a[4], bb[2];
      #pragma unroll
      for (int mi = 0; mi < 4; ++mi)
        a[mi] = *reinterpret_cast<const bf16x8*>(&R1[(mi*16 + l15) * 264 + k0]);
      #pragma unroll
      for (int ni = 0; ni < 2; ++ni)
        bb[ni] = *reinterpret_cast<const bf16x8*>(&R3[(tc*32 + ni*16 + l15) * 264 + k0]);
      #pragma unroll
      for (int mi = 0; mi < 4; ++mi)
        #pragma unroll
        for (int ni = 0; ni < 2; ++ni)
          s[mi][ni] = MFMA16(a[mi], bb[ni], s[mi][ni], 0, 0, 0);
    }
    __syncthreads();
    const float SCL = 0.08838834764831845f;
    unsigned short* P = R1;
    #pragma unroll
    for (int ni = 0; ni < 2; ++ni){
      float m = s[0][ni][0];
      #pragma unroll
      for (int mi = 0; mi < 4; ++mi)
        #pragma unroll
        for (int reg = 0; reg < 4; ++reg) m = fmaxf(m, s[mi][ni][reg]);
      m = fmaxf(m, __shfl_xor(m, 16));
      m = fmaxf(m, __shfl_xor(m, 32));
      float sum = 0.f;
      #pragma unroll
      for (int mi = 0; mi < 4; ++mi)
        #pragma unroll
        for (int reg = 0; reg < 4; ++reg){
          float e = __expf((s[mi][ni][reg] - m) * SCL);
          s[mi][ni][reg] = e; sum += e;
        }
      sum += __shfl_xor(sum, 16);
      sum += __shfl_xor(sum, 32);
      float rs = 1.0f / sum;
      int t = tc*32 + ni*16 + l15;
      #pragma unroll
      for (int mi = 0; mi < 4; ++mi){
        f32x4 pv;
        #pragma unroll
        for (int reg = 0; reg < 4; ++reg) pv[reg] = s[mi][ni][reg] * rs;
        store_bf4(&P[h * 4608 + t * 72 + mi*16 + l4*4], pv);
      }
    }
  }
  __syncthreads();
  {
    int wdh = h * 128 + tc * 64;
    f32x4 acc[4][4];
    #pragma unroll
    for (int i = 0; i < 4; ++i)
      #pragma unroll
      for (int j = 0; j < 4; ++j) acc[i][j] = f32x4{0.f,0.f,0.f,0.f};
    const unsigned short* P = R1;
    #pragma unroll
    for (int ks = 0; ks < 2; ++ks){
      int k0 = ks * 32 + l4 * 8;
      bf16x8 a[4], bb[4];
      #pragma unroll
      for (int mi = 0; mi < 4; ++mi)
        a[mi] = *reinterpret_cast<const bf16x8*>(&R2[(wdh + mi*16 + l15) * 72 + k0]);
      #pragma unroll
      for (int ni = 0; ni < 4; ++ni)
        bb[ni] = *reinterpret_cast<const bf16x8*>(&P[h * 4608 + (ni*16 + l15) * 72 + k0]);
      #pragma unroll
      for (int mi = 0; mi < 4; ++mi)
        #pragma unroll
        for (int ni = 0; ni < 4; ++ni)
          acc[mi][ni] = MFMA16(a[mi], bb[ni], acc[mi][ni], 0, 0, 0);
    }
    #pragma unroll
    for (int mi = 0; mi < 4; ++mi){
      int c0 = wdh + mi*16 + l4*4;
      #pragma unroll
      for (int ni = 0; ni < 4; ++ni)
        store_bf4(&R0[(ni*16 + l15) * 264 + c0], acc[mi][ni]);
    }
  }
  __syncthreads();
  {
    f32x4 acc[4][4];
    #pragma unroll
    for (int i = 0; i < 4; ++i)
      #pragma unroll
      for (int j = 0; j < 4; ++j) acc[i][j] = f32x4{0.f,0.f,0.f,0.f};
    #pragma unroll
    for (int ks = 0; ks < 8; ++ks){
      int k0 = ks * 32 + l4 * 8;
      bf16x8 a[4], bb[4];
      #pragma unroll
      for (int mi = 0; mi < 4; ++mi)
        a[mi] = *reinterpret_cast<const bf16x8*>(Wo + (size_t)((wd + mi*16 + l15) * 256 + k0));
      #pragma unroll
      for (int ni = 0; ni < 4; ++ni)
        bb[ni] = *reinterpret_cast<const bf16x8*>(&R0[(ni*16 + l15) * 264 + k0]);
      #pragma unroll
      for (int mi = 0; mi < 4; ++mi)
        #pragma unroll
        for (int ni = 0; ni < 4; ++ni)
          acc[mi][ni] = MFMA16(a[mi], bb[ni], acc[mi][ni], 0, 0, 0);
    }
    #pragma unroll
    for (int mi = 0; mi < 4; ++mi){
      #pragma unroll
      for (int ni = 0; ni < 4; ++ni){
        int t = ni*16 + l15, thi = t >> 3, twi = t & 7;
        size_t base = (size_t)(wd + mi*16 + l4*4) * g.HW + (size_t)thi * g.W + twi;
        #pragma unroll
        for (int reg = 0; reg < 4; ++reg){
          float res = xsrc[base + (size_t)reg * g.HW];
          float v = acc[mi][ni][reg] + res;
          outp[base + (size_t)reg * g.HW] = fmaxf(v, 0.f);
        }
      }
    }
  }
}

extern "C" void kernel_launch(void* const* d_in, const int* in_sizes, int n_in,
                              void* d_out, int out_size, void* d_ws, size_t ws_size,
                              hipStream_t stream) {
  (void)in_sizes; (void)n_in; (void)out_size;
  const float* f0 = (const float*)d_in[0];
  const float* f1 = (const float*)d_in[1];
  const float* f2 = (const float*)d_in[2];
  const float* f3 = (const float*)d_in[3];
  const float* w1 = (const float*)d_in[4];
  const float* w2 = (const float*)d_in[5];
  float* out = (float*)d_out;

  unsigned short* wbf = (unsigned short*)d_ws;
  const size_t WBF_B = 4194304;       // 2*16*65536 bf16
  const size_t FT_B  = 44564480;      // 87040 tokens * 256 * 2B
  const size_t QKV_B = 22282240;      // 680*64*256*2B
  const size_t need  = WBF_B + 2 * FT_B + 3 * QKV_B;   // 160,169,984

  wcvt_kernel<<<2048, 256, 0, stream>>>(w1, w2, wbf);

  if (ws_size >= need){
    char* base = (char*)d_ws + WBF_B;
    unsigned short* Ft  = (unsigned short*)(base);
    unsigned short* Gt  = (unsigned short*)(base + FT_B);
    unsigned short* Qb  = (unsigned short*)(base + 2 * FT_B);
    unsigned short* Kb  = (unsigned short*)(base + 2 * FT_B + QKV_B);
    unsigned short* VTb = (unsigned short*)(base + 2 * FT_B + 2 * QKV_B);

    xpose_kernel<<<5440, 256, 0, stream>>>(f0, f1, f2, f3, Ft);
    for (int phase = 0; phase < 2; ++phase){
      proj_kernel<<<2040, 256, 0, stream>>>(Ft, Gt, wbf, Qb, Kb, VTb, phase);
      attnop_kernel<<<680, 256, 0, stream>>>(Qb, Kb, VTb, Ft, wbf, Gt, phase);
    }
    untrans_kernel<<<5440, 256, 0, stream>>>(Gt, out);
  } else {
    swin_phase<<<680, 256, 0, stream>>>(f0, f1, f2, f3, wbf, out, 0);
    swin_phase<<<680, 256, 0, stream>>>(f0, f1, f2, f3, wbf, out, 1);
  }
}

// Round 7
// 272.934 us; speedup vs baseline: 1.5613x; 1.5613x over previous
//
#include <hip/hip_runtime.h>

// Swin cross-attention pipeline v7 for MI355X.
// v6 regressed (one-GEMM-per-block destroyed reuse: FETCH 28->305MB). v7 =
// v5 structure (one block per window, K/V/Q in-block => weights+tokens reused)
// but with ONE 36.9KB union LDS tile flushed sequentially (K, V, then Q)
// instead of v5's 70.6KB dual tile -> 4 blocks/CU instead of 2.
// attnop (attention + Wo fused, O stays in LDS) unchanged from v5.

using bf16x8 = __attribute__((ext_vector_type(8))) __bf16;
using f32x4  = __attribute__((ext_vector_type(4))) float;
using u16x4  = __attribute__((ext_vector_type(4))) unsigned short;
using u16x8  = __attribute__((ext_vector_type(8))) unsigned short;

__device__ __forceinline__ unsigned short f2bf(float f){
  unsigned int x = __float_as_uint(f);
  x += 0x7FFFu + ((x >> 16) & 1u);          // RNE
  return (unsigned short)(x >> 16);
}
__device__ __forceinline__ float bf2f(unsigned short u){
  return __uint_as_float((unsigned int)u << 16);
}
__device__ __forceinline__ void store_bf4(unsigned short* dst, f32x4 v){
  u16x4 o;
  o[0]=f2bf(v[0]); o[1]=f2bf(v[1]); o[2]=f2bf(v[2]); o[3]=f2bf(v[3]);
  *reinterpret_cast<u16x4*>(dst) = o;
}

#define MFMA16 __builtin_amdgcn_mfma_f32_16x16x32_bf16

__global__ void wcvt_kernel(const float* __restrict__ w1,
                            const float* __restrict__ w2,
                            unsigned short* __restrict__ dst){
  int i = blockIdx.x * 256 + threadIdx.x;
  const float4* src = (i < 262144) ? (reinterpret_cast<const float4*>(w1) + i)
                                   : (reinterpret_cast<const float4*>(w2) + (i - 262144));
  float4 v = *src;
  u16x4 o; o[0]=f2bf(v.x); o[1]=f2bf(v.y); o[2]=f2bf(v.z); o[3]=f2bf(v.w);
  reinterpret_cast<u16x4*>(dst)[i] = o;
}

// ---- transpose fp32 [C,HW] -> bf16 Ft[token][c] -----------------------------
__global__ __launch_bounds__(256, 2) void xpose_kernel(
    const float* __restrict__ g0, const float* __restrict__ g1,
    const float* __restrict__ g2, const float* __restrict__ g3,
    unsigned short* __restrict__ Ft)
{
  __shared__ float T[64][65];
  int bid = blockIdx.x;
  int r; const float* feat; int Hl; size_t tbase;
  if (bid < 4096){ r = bid;        feat = g0; Hl = 128; tbase = 0; }
  else if (bid < 5120){ r = bid - 4096; feat = g1; Hl = 64;  tbase = 65536; }
  else if (bid < 5376){ r = bid - 5120; feat = g2; Hl = 32;  tbase = 81920; }
  else { r = bid - 5376; feat = g3; Hl = 16;  tbase = 86016; }
  size_t HW = (size_t)Hl * Hl;
  int hw64 = (int)(HW >> 6);
  int bat = r / (4 * hw64);
  int r2 = r - bat * 4 * hw64;
  int ct = r2 / hw64, hwt = r2 - ct * hw64;

  const float* src = feat + (size_t)bat * HW * 256 + (size_t)(ct * 64) * HW + (size_t)hwt * 64;
  int tid = threadIdx.x;
  int cq = tid >> 4, hw0 = (tid & 15) * 4;
  #pragma unroll
  for (int p = 0; p < 4; ++p){
    int c = p * 16 + cq;
    const float* sp = src + (size_t)c * HW + hw0;
    float4 v = *reinterpret_cast<const float4*>(sp);
    T[c][hw0] = v.x; T[c][hw0+1] = v.y; T[c][hw0+2] = v.z; T[c][hw0+3] = v.w;
  }
  __syncthreads();
  unsigned short* dst = Ft + (tbase + (size_t)bat * HW + (size_t)hwt * 64) * 256 + ct * 64;
  #pragma unroll
  for (int p = 0; p < 2; ++p){
    int id = p * 256 + tid;
    int t = id >> 3, c0 = (id & 7) * 8;
    u16x8 o;
    #pragma unroll
    for (int j = 0; j < 8; ++j) o[j] = f2bf(T[c0 + j][t]);
    *reinterpret_cast<u16x8*>(dst + (size_t)t * 256 + c0) = o;
  }
}

// ---- transpose back: Gt[token][c] bf16 -> fp32 out [C,HW], ALL 4 batches ----
__global__ __launch_bounds__(256, 2) void untrans_kernel(
    const unsigned short* __restrict__ Gt, float* __restrict__ outb)
{
  __shared__ float T[64][65];
  int bid = blockIdx.x;
  int r; int Hl; size_t tbase, ooff;
  if (bid < 4096){ r = bid;        Hl = 128; tbase = 0;     ooff = 0; }
  else if (bid < 5120){ r = bid - 4096; Hl = 64; tbase = 65536; ooff = 16777216; }
  else if (bid < 5376){ r = bid - 5120; Hl = 32; tbase = 81920; ooff = 20971520; }
  else { r = bid - 5376; Hl = 16; tbase = 86016; ooff = 22020096; }
  size_t HW = (size_t)Hl * Hl;
  int hw64 = (int)(HW >> 6);
  int bat = r / (4 * hw64);
  int r2 = r - bat * 4 * hw64;
  int ct = r2 / hw64, hwt = r2 - ct * hw64;

  const unsigned short* src = Gt + (tbase + (size_t)bat * HW + (size_t)hwt * 64) * 256 + ct * 64;
  int tid = threadIdx.x;
  #pragma unroll
  for (int p = 0; p < 2; ++p){
    int id = p * 256 + tid;
    int t = id >> 3, c0 = (id & 7) * 8;
    u16x8 v = *reinterpret_cast<const u16x8*>(src + (size_t)t * 256 + c0);
    #pragma unroll
    for (int j = 0; j < 8; ++j) T[t][c0 + j] = bf2f(v[j]);
  }
  __syncthreads();
  float* dst = outb + ooff + (size_t)bat * HW * 256 + (size_t)(ct * 64) * HW + (size_t)hwt * 64;
  int cq = tid >> 4, hw0 = (tid & 15) * 4;
  #pragma unroll
  for (int p = 0; p < 4; ++p){
    int c = p * 16 + cq;
    float4 v;
    v.x = T[hw0][c]; v.y = T[hw0+1][c]; v.z = T[hw0+2][c]; v.w = T[hw0+3][c];
    *reinterpret_cast<float4*>(dst + (size_t)c * HW + hw0) = v;
  }
}

// ---- window geometry --------------------------------------------------------
struct WinGeo { int H, W, b, lvl; size_t HW, winoff, tbase, ooff; };

__device__ __forceinline__ WinGeo decode_win(int win){
  WinGeo g; int wloc;
  if (win < 512){ g.lvl = 0; wloc = win;      g.H = 128; g.tbase = 0;     g.ooff = 0; }
  else if (win < 640){ g.lvl = 1; wloc = win - 512; g.H = 64; g.tbase = 65536; g.ooff = 16777216; }
  else if (win < 672){ g.lvl = 2; wloc = win - 640; g.H = 32; g.tbase = 81920; g.ooff = 20971520; }
  else { g.lvl = 3; wloc = win - 672; g.H = 16; g.tbase = 86016; g.ooff = 22020096; }
  g.W = g.H; g.HW = (size_t)g.H * g.W;
  int nww = g.H >> 3, npb = nww * nww;
  g.b = wloc / npb;
  int r = wloc - g.b * npb;
  int wh = r / nww, ww = r - wh * nww;
  g.winoff = (size_t)(wh * 8) * g.W + (size_t)(ww * 8);
  return g;
}

// coalesced flush: LDS [64][264] tile -> global [64][256] bf16 rows
__device__ __forceinline__ void flush_tile_td(const unsigned short* __restrict__ st,
    unsigned short* __restrict__ dst, int tid){
  #pragma unroll
  for (int p = 0; p < 8; ++p){
    int id = p * 256 + tid;
    int t = id >> 5, c = (id & 31) * 8;
    *reinterpret_cast<u16x8*>(dst + (size_t)t * 256 + c) =
      *reinterpret_cast<const u16x8*>(st + t * 264 + c);
  }
}
// coalesced flush: LDS [256][72] tile -> global [256][64] bf16 rows
__device__ __forceinline__ void flush_tile_vt(const unsigned short* __restrict__ st,
    unsigned short* __restrict__ dst, int tid){
  #pragma unroll
  for (int p = 0; p < 8; ++p){
    int id = p * 256 + tid;
    int d = id >> 3, u = (id & 7) * 8;
    *reinterpret_cast<u16x8*>(dst + (size_t)d * 64 + u) =
      *reinterpret_cast<const u16x8*>(st + d * 72 + u);
  }
}

// ---- P1: per-window K,V,Q GEMMs sequentially through one union LDS tile -----
__global__ __launch_bounds__(256, 4) void proj_kernel(
    const unsigned short* __restrict__ Ft, const unsigned short* __restrict__ Gt,
    const unsigned short* __restrict__ wball,
    unsigned short* __restrict__ Qb, unsigned short* __restrict__ Kb,
    unsigned short* __restrict__ VTb, int phase)
{
  __shared__ alignas(16) unsigned short ST[256*72];   // 36864 B union tile
  int win = blockIdx.x;
  WinGeo g = decode_win(win);
  int tid = threadIdx.x;
  int w = tid >> 6, l = tid & 63, l15 = l & 15, l4 = l >> 4, wd = w * 64;

  int batx = (phase == 0) ? g.b : g.b + 2;
  const unsigned short* Sx = Ft + (g.tbase + (size_t)batx * g.HW) * 256;
  const unsigned short* Sy = (phase == 0)
      ? Ft + (g.tbase + (size_t)(g.b + 2) * g.HW) * 256
      : Gt + (g.tbase + (size_t)g.b * g.HW) * 256;

  size_t rowo[4];
  #pragma unroll
  for (int ni = 0; ni < 4; ++ni){
    int t = ni * 16 + l15;
    rowo[ni] = ((size_t)g.winoff + (size_t)(t >> 3) * g.W + (t & 7)) * 256;
  }
  const unsigned short* Wbase = wball + ((size_t)(phase * 16 + g.lvl * 4) << 16);
  const unsigned short* Wq = Wbase;
  const unsigned short* Wk = Wbase + 65536;
  const unsigned short* Wv = Wbase + 131072;
  size_t woff = (size_t)win << 14;

  // ---- K GEMM: K^T = Wk * yw^T -> K[t][d] ----
  {
    f32x4 acc[4][4];
    #pragma unroll
    for (int i = 0; i < 4; ++i)
      #pragma unroll
      for (int j = 0; j < 4; ++j) acc[i][j] = f32x4{0.f,0.f,0.f,0.f};
    #pragma unroll
    for (int ks = 0; ks < 8; ++ks){
      int k0 = ks * 32 + l4 * 8;
      bf16x8 tf[4], wf[4];
      #pragma unroll
      for (int i = 0; i < 4; ++i){
        tf[i] = *reinterpret_cast<const bf16x8*>(Sy + rowo[i] + k0);
        wf[i] = *reinterpret_cast<const bf16x8*>(Wk + (size_t)((wd + i*16 + l15) * 256 + k0));
      }
      __builtin_amdgcn_s_setprio(1);
      #pragma unroll
      for (int mi = 0; mi < 4; ++mi)
        #pragma unroll
        for (int ni = 0; ni < 4; ++ni)
          acc[mi][ni] = MFMA16(wf[mi], tf[ni], acc[mi][ni], 0, 0, 0);
      __builtin_amdgcn_s_setprio(0);
    }
    #pragma unroll
    for (int mi = 0; mi < 4; ++mi){
      int d0 = wd + mi*16 + l4*4;
      #pragma unroll
      for (int ni = 0; ni < 4; ++ni)
        store_bf4(&ST[(ni*16 + l15) * 264 + d0], acc[mi][ni]);
    }
    __syncthreads();
    flush_tile_td(ST, Kb + woff, tid);
  }

  // ---- V GEMM: V = yw * Wv^T -> V^T[d][u] ----
  {
    f32x4 acc[4][4];
    #pragma unroll
    for (int i = 0; i < 4; ++i)
      #pragma unroll
      for (int j = 0; j < 4; ++j) acc[i][j] = f32x4{0.f,0.f,0.f,0.f};
    #pragma unroll
    for (int ks = 0; ks < 8; ++ks){
      int k0 = ks * 32 + l4 * 8;
      bf16x8 tf[4], wf[4];
      #pragma unroll
      for (int i = 0; i < 4; ++i){
        tf[i] = *reinterpret_cast<const bf16x8*>(Sy + rowo[i] + k0);
        wf[i] = *reinterpret_cast<const bf16x8*>(Wv + (size_t)((wd + i*16 + l15) * 256 + k0));
      }
      __builtin_amdgcn_s_setprio(1);
      #pragma unroll
      for (int mi = 0; mi < 4; ++mi)
        #pragma unroll
        for (int ni = 0; ni < 4; ++ni)
          acc[mi][ni] = MFMA16(tf[mi], wf[ni], acc[mi][ni], 0, 0, 0);
      __builtin_amdgcn_s_setprio(0);
    }
    __syncthreads();   // all K-flush LDS reads complete before overwrite
    #pragma unroll
    for (int mi = 0; mi < 4; ++mi){
      int u0 = mi*16 + l4*4;
      #pragma unroll
      for (int ni = 0; ni < 4; ++ni)
        store_bf4(&ST[(wd + ni*16 + l15) * 72 + u0], acc[mi][ni]);
    }
    __syncthreads();
    flush_tile_vt(ST, VTb + woff, tid);
  }

  // ---- Q GEMM: Q^T = Wq * xw^T -> Q[t][d] ----
  {
    f32x4 acc[4][4];
    #pragma unroll
    for (int i = 0; i < 4; ++i)
      #pragma unroll
      for (int j = 0; j < 4; ++j) acc[i][j] = f32x4{0.f,0.f,0.f,0.f};
    #pragma unroll
    for (int ks = 0; ks < 8; ++ks){
      int k0 = ks * 32 + l4 * 8;
      bf16x8 tf[4], wf[4];
      #pragma unroll
      for (int i = 0; i < 4; ++i){
        tf[i] = *reinterpret_cast<const bf16x8*>(Sx + rowo[i] + k0);
        wf[i] = *reinterpret_cast<const bf16x8*>(Wq + (size_t)((wd + i*16 + l15) * 256 + k0));
      }
      __builtin_amdgcn_s_setprio(1);
      #pragma unroll
      for (int mi = 0; mi < 4; ++mi)
        #pragma unroll
        for (int ni = 0; ni < 4; ++ni)
          acc[mi][ni] = MFMA16(wf[mi], tf[ni], acc[mi][ni], 0, 0, 0);
      __builtin_amdgcn_s_setprio(0);
    }
    __syncthreads();   // all V-flush LDS reads complete before overwrite
    #pragma unroll
    for (int mi = 0; mi < 4; ++mi){
      int d0 = wd + mi*16 + l4*4;
      #pragma unroll
      for (int ni = 0; ni < 4; ++ni)
        store_bf4(&ST[(ni*16 + l15) * 264 + d0], acc[mi][ni]);
    }
    __syncthreads();
    flush_tile_td(ST, Qb + woff, tid);
  }
}

// ---- P2: attention + output projection fused per window ---------------------
__global__ __launch_bounds__(256, 3) void attnop_kernel(
    const unsigned short* __restrict__ Qb, const unsigned short* __restrict__ Kb,
    const unsigned short* __restrict__ VTb, const unsigned short* __restrict__ Ft,
    const unsigned short* __restrict__ wball,
    unsigned short* __restrict__ Gt, int phase)
{
  __shared__ alignas(16) unsigned short UB[64*264];   // P -> O -> out tile
  int win = blockIdx.x;
  WinGeo g = decode_win(win);
  size_t woff = (size_t)win << 14;
  const unsigned short* Qw = Qb + woff;
  const unsigned short* Kw = Kb + woff;
  const unsigned short* VTw = VTb + woff;

  int tid = threadIdx.x;
  int w = tid >> 6, l = tid & 63, l15 = l & 15, l4 = l >> 4, wd = w * 64;
  int h = w >> 1, tc = w & 1;

  int bat = (phase == 0) ? g.b : g.b + 2;
  const unsigned short* Xres = Ft + (g.tbase + (size_t)bat * g.HW) * 256;
  unsigned short* Gout = Gt + (g.tbase + (size_t)bat * g.HW) * 256;
  const unsigned short* Wo = wball + ((size_t)(phase * 16 + g.lvl * 4 + 3) << 16);

  // ---- S^T[u][t] per head ----
  f32x4 s[4][2];
  #pragma unroll
  for (int i = 0; i < 4; ++i){ s[i][0] = f32x4{0.f,0.f,0.f,0.f}; s[i][1] = f32x4{0.f,0.f,0.f,0.f}; }
  #pragma unroll
  for (int ks = 0; ks < 4; ++ks){
    int k0 = h * 128 + ks * 32 + l4 * 8;
    bf16x8 a[4], bb[2];
    #pragma unroll
    for (int mi = 0; mi < 4; ++mi)
      a[mi] = *reinterpret_cast<const bf16x8*>(Kw + (size_t)(mi*16 + l15) * 256 + k0);
    #pragma unroll
    for (int ni = 0; ni < 2; ++ni)
      bb[ni] = *reinterpret_cast<const bf16x8*>(Qw + (size_t)(tc*32 + ni*16 + l15) * 256 + k0);
    __builtin_amdgcn_s_setprio(1);
    #pragma unroll
    for (int mi = 0; mi < 4; ++mi)
      #pragma unroll
      for (int ni = 0; ni < 2; ++ni)
        s[mi][ni] = MFMA16(a[mi], bb[ni], s[mi][ni], 0, 0, 0);
    __builtin_amdgcn_s_setprio(0);
  }

  // ---- softmax over u (per column t), P -> LDS bf16 ----
  const float SCL = 0.08838834764831845f;   // 1/sqrt(128)
  #pragma unroll
  for (int ni = 0; ni < 2; ++ni){
    float m = s[0][ni][0];
    #pragma unroll
    for (int mi = 0; mi < 4; ++mi)
      #pragma unroll
      for (int reg = 0; reg < 4; ++reg) m = fmaxf(m, s[mi][ni][reg]);
    m = fmaxf(m, __shfl_xor(m, 16));
    m = fmaxf(m, __shfl_xor(m, 32));
    float sum = 0.f;
    #pragma unroll
    for (int mi = 0; mi < 4; ++mi)
      #pragma unroll
      for (int reg = 0; reg < 4; ++reg){
        float e = __expf((s[mi][ni][reg] - m) * SCL);
        s[mi][ni][reg] = e; sum += e;
      }
    sum += __shfl_xor(sum, 16);
    sum += __shfl_xor(sum, 32);
    float rs = 1.0f / sum;
    int t = tc*32 + ni*16 + l15;
    #pragma unroll
    for (int mi = 0; mi < 4; ++mi){
      f32x4 pv;
      #pragma unroll
      for (int reg = 0; reg < 4; ++reg) pv[reg] = s[mi][ni][reg] * rs;
      store_bf4(&UB[h * 4608 + t * 72 + mi*16 + l4*4], pv);
    }
  }
  __syncthreads();

  // ---- O^T[c][t] = V^T * P^T ----
  f32x4 acc[4][4];
  #pragma unroll
  for (int i = 0; i < 4; ++i)
    #pragma unroll
    for (int j = 0; j < 4; ++j) acc[i][j] = f32x4{0.f,0.f,0.f,0.f};
  #pragma unroll
  for (int ks = 0; ks < 2; ++ks){
    int k0 = ks * 32 + l4 * 8;
    bf16x8 a[4], bb[4];
    #pragma unroll
    for (int mi = 0; mi < 4; ++mi)
      a[mi] = *reinterpret_cast<const bf16x8*>(VTw + (size_t)(wd + mi*16 + l15) * 64 + k0);
    #pragma unroll
    for (int ni = 0; ni < 4; ++ni)
      bb[ni] = *reinterpret_cast<const bf16x8*>(&UB[h * 4608 + (ni*16 + l15) * 72 + k0]);
    __builtin_amdgcn_s_setprio(1);
    #pragma unroll
    for (int mi = 0; mi < 4; ++mi)
      #pragma unroll
      for (int ni = 0; ni < 4; ++ni)
        acc[mi][ni] = MFMA16(a[mi], bb[ni], acc[mi][ni], 0, 0, 0);
    __builtin_amdgcn_s_setprio(0);
  }
  __syncthreads();   // all P reads done; O tile may overwrite UB
  #pragma unroll
  for (int mi = 0; mi < 4; ++mi){
    int c0 = wd + mi*16 + l4*4;
    #pragma unroll
    for (int ni = 0; ni < 4; ++ni)
      store_bf4(&UB[(ni*16 + l15) * 264 + c0], acc[mi][ni]);
  }
  __syncthreads();

  // ---- out^T = Wo * o^T (O fragments from LDS) ----
  #pragma unroll
  for (int i = 0; i < 4; ++i)
    #pragma unroll
    for (int j = 0; j < 4; ++j) acc[i][j] = f32x4{0.f,0.f,0.f,0.f};
  #pragma unroll
  for (int ks = 0; ks < 8; ++ks){
    int k0 = ks * 32 + l4 * 8;
    bf16x8 a[4], bb[4];
    #pragma unroll
    for (int mi = 0; mi < 4; ++mi)
      a[mi] = *reinterpret_cast<const bf16x8*>(Wo + (size_t)((wd + mi*16 + l15) * 256 + k0));
    #pragma unroll
    for (int ni = 0; ni < 4; ++ni)
      bb[ni] = *reinterpret_cast<const bf16x8*>(&UB[(ni*16 + l15) * 264 + k0]);
    __builtin_amdgcn_s_setprio(1);
    #pragma unroll
    for (int mi = 0; mi < 4; ++mi)
      #pragma unroll
      for (int ni = 0; ni < 4; ++ni)
        acc[mi][ni] = MFMA16(a[mi], bb[ni], acc[mi][ni], 0, 0, 0);
    __builtin_amdgcn_s_setprio(0);
  }
  __syncthreads();   // all O reads done; out tile may overwrite UB
  #pragma unroll
  for (int mi = 0; mi < 4; ++mi){
    int c0 = wd + mi*16 + l4*4;
    #pragma unroll
    for (int ni = 0; ni < 4; ++ni)
      store_bf4(&UB[(ni*16 + l15) * 264 + c0], acc[mi][ni]);
  }
  __syncthreads();

  // ---- fused flush: out + residual, relu, 16B coalesced -> Gt ----
  #pragma unroll
  for (int p = 0; p < 8; ++p){
    int id = p * 256 + tid;
    int t = id >> 5, c = (id & 31) * 8;
    size_t ro = ((size_t)g.winoff + (size_t)(t >> 3) * g.W + (t & 7)) * 256 + c;
    u16x8 ov = *reinterpret_cast<const u16x8*>(&UB[t * 264 + c]);
    u16x8 rv = *reinterpret_cast<const u16x8*>(Xres + ro);
    u16x8 o;
    #pragma unroll
    for (int j = 0; j < 8; ++j)
      o[j] = f2bf(fmaxf(bf2f(ov[j]) + bf2f(rv[j]), 0.f));
    *reinterpret_cast<u16x8*>(Gout + ro) = o;
  }
}

// ======================= round-1 fused fallback ==============================
__global__ __launch_bounds__(256, 1) void swin_phase(
    const float* __restrict__ g0, const float* __restrict__ g1,
    const float* __restrict__ g2, const float* __restrict__ g3,
    const unsigned short* __restrict__ wball,
    float* __restrict__ outb, int phase)
{
  __shared__ alignas(16) unsigned short R0[64*264];
  __shared__ alignas(16) unsigned short R1[64*264];
  __shared__ alignas(16) unsigned short R2[256*72];
  __shared__ alignas(16) unsigned short R3[64*264];

  int bid = blockIdx.x;
  WinGeo g = decode_win(bid);
  const float* feat = (g.lvl == 0) ? g0 : (g.lvl == 1) ? g1 : (g.lvl == 2) ? g2 : g3;
  size_t CHW = g.HW * 256;

  const float* xsrc; const float* ysrc; float* outp;
  if (phase == 0){
    xsrc = feat + (size_t)g.b * CHW + g.winoff;
    ysrc = feat + (size_t)(g.b + 2) * CHW + g.winoff;
    outp = outb + g.ooff + (size_t)g.b * CHW + g.winoff;
  } else {
    xsrc = feat + (size_t)(g.b + 2) * CHW + g.winoff;
    ysrc = outb + g.ooff + (size_t)g.b * CHW + g.winoff;
    outp = outb + g.ooff + (size_t)(g.b + 2) * CHW + g.winoff;
  }
  const unsigned short* Wq = wball + ((size_t)(phase * 16 + g.lvl * 4) << 16);
  const unsigned short* Wk = Wq + 65536;
  const unsigned short* Wv = Wq + 2 * 65536;
  const unsigned short* Wo = Wq + 3 * 65536;

  int tid = threadIdx.x;
  int w = tid >> 6, l = tid & 63, l15 = l & 15, l4 = l >> 4, wd = w * 64;
  int hi0 = l >> 3, wi0 = l & 7;

  {
    const float* p0 = ysrc + (size_t)hi0 * g.W + wi0;
    #pragma unroll
    for (int oc = 0; oc < 8; ++oc){
      int c0 = (oc * 4 + w) * 8;
      const float* p = p0 + (size_t)c0 * g.HW;
      u16x8 uv;
      #pragma unroll
      for (int j = 0; j < 8; ++j) uv[j] = f2bf(p[(size_t)j * g.HW]);
      *reinterpret_cast<u16x8*>(&R0[l * 264 + c0]) = uv;
    }
  }
  __syncthreads();
  {
    f32x4 acc[4][4];
    #pragma unroll
    for (int i = 0; i < 4; ++i)
      #pragma unroll
      for (int j = 0; j < 4; ++j) acc[i][j] = f32x4{0.f,0.f,0.f,0.f};
    #pragma unroll
    for (int ks = 0; ks < 8; ++ks){
      int k0 = ks * 32 + l4 * 8;
      bf16x8 a[4], bb[4];
      #pragma unroll
      for (int mi = 0; mi < 4; ++mi)
        a[mi] = *reinterpret_cast<const bf16x8*>(Wk + (size_t)((wd + mi*16 + l15) * 256 + k0));
      #pragma unroll
      for (int ni = 0; ni < 4; ++ni)
        bb[ni] = *reinterpret_cast<const bf16x8*>(&R0[(ni*16 + l15) * 264 + k0]);
      #pragma unroll
      for (int mi = 0; mi < 4; ++mi)
        #pragma unroll
        for (int ni = 0; ni < 4; ++ni)
          acc[mi][ni] = MFMA16(a[mi], bb[ni], acc[mi][ni], 0, 0, 0);
    }
    #pragma unroll
    for (int mi = 0; mi < 4; ++mi){
      int d0 = wd + mi*16 + l4*4;
      #pragma unroll
      for (int ni = 0; ni < 4; ++ni)
        store_bf4(&R1[(ni*16 + l15) * 264 + d0], acc[mi][ni]);
    }
  }
  {
    f32x4 acc[4][4];
    #pragma unroll
    for (int i = 0; i < 4; ++i)
      #pragma unroll
      for (int j = 0; j < 4; ++j) acc[i][j] = f32x4{0.f,0.f,0.f,0.f};
    #pragma unroll
    for (int ks = 0; ks < 8; ++ks){
      int k0 = ks * 32 + l4 * 8;
      bf16x8 a[4], bb[4];
      #pragma unroll
      for (int mi = 0; mi < 4; ++mi)
        a[mi] = *reinterpret_cast<const bf16x8*>(&R0[(mi*16 + l15) * 264 + k0]);
      #pragma unroll
      for (int ni = 0; ni < 4; ++ni)
        bb[ni] = *reinterpret_cast<const bf16x8*>(Wv + (size_t)((wd + ni*16 + l15) * 256 + k0));
      #pragma unroll
      for (int mi = 0; mi < 4; ++mi)
        #pragma unroll
        for (int ni = 0; ni < 4; ++ni)
          acc[mi][ni] = MFMA16(a[mi], bb[ni], acc[mi][ni], 0, 0, 0);
    }
    #pragma unroll
    for (int mi = 0; mi < 4; ++mi){
      int u0 = mi*16 + l4*4;
      #pragma unroll
      for (int ni = 0; ni < 4; ++ni)
        store_bf4(&R2[(wd + ni*16 + l15) * 72 + u0], acc[mi][ni]);
    }
  }
  __syncthreads();
  {
    const float* p0 = xsrc + (size_t)hi0 * g.W + wi0;
    #pragma unroll
    for (int oc = 0; oc < 8; ++oc){
      int c0 = (oc * 4 + w) * 8;
      const float* p = p0 + (size_t)c0 * g.HW;
      u16x8 uv;
      #pragma unroll
      for (int j = 0; j < 8; ++j) uv[j] = f2bf(p[(size_t)j * g.HW]);
      *reinterpret_cast<u16x8*>(&R0[l * 264 + c0]) = uv;
    }
  }
  __syncthreads();
  {
    f32x4 acc[4][4];
    #pragma unroll
    for (int i = 0; i < 4; ++i)
      #pragma unroll
      for (int j = 0; j < 4; ++j) acc[i][j] = f32x4{0.f,0.f,0.f,0.f};
    #pragma unroll
    for (int ks = 0; ks < 8; ++ks){
      int k0 = ks * 32 + l4 * 8;
      bf16x8 a[4], bb[4];
      #pragma unroll
      for (int mi = 0; mi < 4; ++mi)
        a[mi] = *reinterpret_cast<const bf16x8*>(Wq + (size_t)((wd + mi*16 + l15) * 256 + k0));
      #pragma unroll
      for (int ni = 0; ni < 4; ++ni)
        bb[ni] = *reinterpret_cast<const bf16x8*>(&R0[(ni*16 + l15) * 264 + k0]);
      #pragma unroll
      for (int mi = 0; mi < 4; ++mi)
        #pragma unroll
        for (int ni = 0; ni < 4; ++ni)
          acc[mi][ni] = MFMA16(a[mi], bb[ni], acc[mi][ni], 0, 0, 0);
    }
    #pragma unroll
    for (int mi = 0; mi < 4; ++mi){
      int d0 = wd + mi*16 + l4*4;
      #pragma unroll
      for (int ni = 0; ni < 4; ++ni)
        store_bf4(&R3[(ni*16 + l15) * 264 + d0], acc[mi][ni]);
    }
  }
  __syncthreads();

  int h = w >> 1, tc = w & 1;
  {
    f32x4 s[4][2];
    #pragma unroll
    for (int i = 0; i < 4; ++i){ s[i][0] = f32x4{0.f,0.f,0.f,0.f}; s[i][1] = f32x4{0.f,0.f,0.f,0.f}; }
    #pragma unroll
    for (int ks = 0; ks < 4; ++ks){
      int k0 = h * 128 + ks * 32 + l4 * 8;
      bf16x8 a[4], bb[2];
      #pragma unroll
      for (int mi = 0; mi < 4; ++mi)
        a[mi] = *reinterpret_cast<const bf16x8*>(&R1[(mi*16 + l15) * 264 + k0]);
      #pragma unroll
      for (int ni = 0; ni < 2; ++ni)
        bb[ni] = *reinterpret_cast<const bf16x8*>(&R3[(tc*32 + ni*16 + l15) * 264 + k0]);
      #pragma unroll
      for (int mi = 0; mi < 4; ++mi)
        #pragma unroll
        for (int ni = 0; ni < 2; ++ni)
          s[mi][ni] = MFMA16(a[mi], bb[ni], s[mi][ni], 0, 0, 0);
    }
    __syncthreads();
    const float SCL = 0.08838834764831845f;
    unsigned short* P = R1;
    #pragma unroll
    for (int ni = 0; ni < 2; ++ni){
      float m = s[0][ni][0];
      #pragma unroll
      for (int mi = 0; mi < 4; ++mi)
        #pragma unroll
        for (int reg = 0; reg < 4; ++reg) m = fmaxf(m, s[mi][ni][reg]);
      m = fmaxf(m, __shfl_xor(m, 16));
      m = fmaxf(m, __shfl_xor(m, 32));
      float sum = 0.f;
      #pragma unroll
      for (int mi = 0; mi < 4; ++mi)
        #pragma unroll
        for (int reg = 0; reg < 4; ++reg){
          float e = __expf((s[mi][ni][reg] - m) * SCL);
          s[mi][ni][reg] = e; sum += e;
        }
      sum += __shfl_xor(sum, 16);
      sum += __shfl_xor(sum, 32);
      float rs = 1.0f / sum;
      int t = tc*32 + ni*16 + l15;
      #pragma unroll
      for (int mi = 0; mi < 4; ++mi){
        f32x4 pv;
        #pragma unroll
        for (int reg = 0; reg < 4; ++reg) pv[reg] = s[mi][ni][reg] * rs;
        store_bf4(&P[h * 4608 + t * 72 + mi*16 + l4*4], pv);
      }
    }
  }
  __syncthreads();
  {
    int wdh = h * 128 + tc * 64;
    f32x4 acc[4][4];
    #pragma unroll
    for (int i = 0; i < 4; ++i)
      #pragma unroll
      for (int j = 0; j < 4; ++j) acc[i][j] = f32x4{0.f,0.f,0.f,0.f};
    const unsigned short* P = R1;
    #pragma unroll
    for (int ks = 0; ks < 2; ++ks){
      int k0 = ks * 32 + l4 * 8;
      bf16x8 a[4], bb[4];
      #pragma unroll
      for (int mi = 0; mi < 4; ++mi)
        a[mi] = *reinterpret_cast<const bf16x8*>(&R2[(wdh + mi*16 + l15) * 72 + k0]);
      #pragma unroll
      for (int ni = 0; ni < 4; ++ni)
        bb[ni] = *reinterpret_cast<const bf16x8*>(&P[h * 4608 + (ni*16 + l15) * 72 + k0]);
      #pragma unroll
      for (int mi = 0; mi < 4; ++mi)
        #pragma unroll
        for (int ni = 0; ni < 4; ++ni)
          acc[mi][ni] = MFMA16(a[mi], bb[ni], acc[mi][ni], 0, 0, 0);
    }
    #pragma unroll
    for (int mi = 0; mi < 4; ++mi){
      int c0 = wdh + mi*16 + l4*4;
      #pragma unroll
      for (int ni = 0; ni < 4; ++ni)
        store_bf4(&R0[(ni*16 + l15) * 264 + c0], acc[mi][ni]);
    }
  }
  __syncthreads();
  {
    f32x4 acc[4][4];
    #pragma unroll
    for (int i = 0; i < 4; ++i)
      #pragma unroll
      for (int j = 0; j < 4; ++j) acc[i][j] = f32x4{0.f,0.f,0.f,0.f};
    #pragma unroll
    for (int ks = 0; ks < 8; ++ks){
      int k0 = ks * 32 + l4 * 8;
      bf16x8 a[4], bb[4];
      #pragma unroll
      for (int mi = 0; mi < 4; ++mi)
        a[mi] = *reinterpret_cast<const bf16x8*>(Wo + (size_t)((wd + mi*16 + l15) * 256 + k0));
      #pragma unroll
      for (int ni = 0; ni < 4; ++ni)
        bb[ni] = *reinterpret_cast<const bf16x8*>(&R0[(ni*16 + l15) * 264 + k0]);
      #pragma unroll
      for (int mi = 0; mi < 4; ++mi)
        #pragma unroll
        for (int ni = 0; ni < 4; ++ni)
          acc[mi][ni] = MFMA16(a[mi], bb[ni], acc[mi][ni], 0, 0, 0);
    }
    #pragma unroll
    for (int mi = 0; mi < 4; ++mi){
      #pragma unroll
      for (int ni = 0; ni < 4; ++ni){
        int t = ni*16 + l15, thi = t >> 3, twi = t & 7;
        size_t base = (size_t)(wd + mi*16 + l4*4) * g.HW + (size_t)thi * g.W + twi;
        #pragma unroll
        for (int reg = 0; reg < 4; ++reg){
          float res = xsrc[base + (size_t)reg * g.HW];
          float v = acc[mi][ni][reg] + res;
          outp[base + (size_t)reg * g.HW] = fmaxf(v, 0.f);
        }
      }
    }
  }
}

extern "C" void kernel_launch(void* const* d_in, const int* in_sizes, int n_in,
                              void* d_out, int out_size, void* d_ws, size_t ws_size,
                              hipStream_t stream) {
  (void)in_sizes; (void)n_in; (void)out_size;
  const float* f0 = (const float*)d_in[0];
  const float* f1 = (const float*)d_in[1];
  const float* f2 = (const float*)d_in[2];
  const float* f3 = (const float*)d_in[3];
  const float* w1 = (const float*)d_in[4];
  const float* w2 = (const float*)d_in[5];
  float* out = (float*)d_out;

  unsigned short* wbf = (unsigned short*)d_ws;
  const size_t WBF_B = 4194304;       // 2*16*65536 bf16
  const size_t FT_B  = 44564480;      // 87040 tokens * 256 * 2B
  const size_t QKV_B = 22282240;      // 680*64*256*2B
  const size_t need  = WBF_B + 2 * FT_B + 3 * QKV_B;   // 160,169,984

  wcvt_kernel<<<2048, 256, 0, stream>>>(w1, w2, wbf);

  if (ws_size >= need){
    char* base = (char*)d_ws + WBF_B;
    unsigned short* Ft  = (unsigned short*)(base);
    unsigned short* Gt  = (unsigned short*)(base + FT_B);
    unsigned short* Qb  = (unsigned short*)(base + 2 * FT_B);
    unsigned short* Kb  = (unsigned short*)(base + 2 * FT_B + QKV_B);
    unsigned short* VTb = (unsigned short*)(base + 2 * FT_B + 2 * QKV_B);

    xpose_kernel<<<5440, 256, 0, stream>>>(f0, f1, f2, f3, Ft);
    for (int phase = 0; phase < 2; ++phase){
      proj_kernel<<<680, 256, 0, stream>>>(Ft, Gt, wbf, Qb, Kb, VTb, phase);
      attnop_kernel<<<680, 256, 0, stream>>>(Qb, Kb, VTb, Ft, wbf, Gt, phase);
    }
    untrans_kernel<<<5440, 256, 0, stream>>>(Gt, out);
  } else {
    swin_phase<<<680, 256, 0, stream>>>(f0, f1, f2, f3, wbf, out, 0);
    swin_phase<<<680, 256, 0, stream>>>(f0, f1, f2, f3, wbf, out, 1);
  }
}

// Round 8
// 198.912 us; speedup vs baseline: 2.1423x; 1.3721x over previous
//
#include <hip/hip_runtime.h>

// Swin cross-attention pipeline v8 for MI355X.
// v8 = fully-fused per-window kernel (proj + attention + output-proj in one
// block), eliminating the 134MB/phase Q/K/V global round-trip that kept
// proj pinned at ~84us. LDS 69KB (2 blocks/CU) via aliasing:
//   A[64*264] : K -> P -> O -> out      (33.8 KB)
//   B[256*72] : Q([64][264] view) -> V^T (36.9 KB)
// K/V k-loops interleaved sharing Sy fragments (Sy read once); V acc held in
// registers across Q-GEMM and QK^T, stored to B only after Q dies.
// xpose/untrans/wcvt unchanged. Fallback: round-1 fused kernel.

using bf16x8 = __attribute__((ext_vector_type(8))) __bf16;
using f32x4  = __attribute__((ext_vector_type(4))) float;
using u16x4  = __attribute__((ext_vector_type(4))) unsigned short;
using u16x8  = __attribute__((ext_vector_type(8))) unsigned short;

__device__ __forceinline__ unsigned short f2bf(float f){
  unsigned int x = __float_as_uint(f);
  x += 0x7FFFu + ((x >> 16) & 1u);          // RNE
  return (unsigned short)(x >> 16);
}
__device__ __forceinline__ float bf2f(unsigned short u){
  return __uint_as_float((unsigned int)u << 16);
}
__device__ __forceinline__ void store_bf4(unsigned short* dst, f32x4 v){
  u16x4 o;
  o[0]=f2bf(v[0]); o[1]=f2bf(v[1]); o[2]=f2bf(v[2]); o[3]=f2bf(v[3]);
  *reinterpret_cast<u16x4*>(dst) = o;
}

#define MFMA16 __builtin_amdgcn_mfma_f32_16x16x32_bf16

__global__ void wcvt_kernel(const float* __restrict__ w1,
                            const float* __restrict__ w2,
                            unsigned short* __restrict__ dst){
  int i = blockIdx.x * 256 + threadIdx.x;
  const float4* src = (i < 262144) ? (reinterpret_cast<const float4*>(w1) + i)
                                   : (reinterpret_cast<const float4*>(w2) + (i - 262144));
  float4 v = *src;
  u16x4 o; o[0]=f2bf(v.x); o[1]=f2bf(v.y); o[2]=f2bf(v.z); o[3]=f2bf(v.w);
  reinterpret_cast<u16x4*>(dst)[i] = o;
}

// ---- transpose fp32 [C,HW] -> bf16 Ft[token][c] -----------------------------
__global__ __launch_bounds__(256, 2) void xpose_kernel(
    const float* __restrict__ g0, const float* __restrict__ g1,
    const float* __restrict__ g2, const float* __restrict__ g3,
    unsigned short* __restrict__ Ft)
{
  __shared__ float T[64][65];
  int bid = blockIdx.x;
  int r; const float* feat; int Hl; size_t tbase;
  if (bid < 4096){ r = bid;        feat = g0; Hl = 128; tbase = 0; }
  else if (bid < 5120){ r = bid - 4096; feat = g1; Hl = 64;  tbase = 65536; }
  else if (bid < 5376){ r = bid - 5120; feat = g2; Hl = 32;  tbase = 81920; }
  else { r = bid - 5376; feat = g3; Hl = 16;  tbase = 86016; }
  size_t HW = (size_t)Hl * Hl;
  int hw64 = (int)(HW >> 6);
  int bat = r / (4 * hw64);
  int r2 = r - bat * 4 * hw64;
  int ct = r2 / hw64, hwt = r2 - ct * hw64;

  const float* src = feat + (size_t)bat * HW * 256 + (size_t)(ct * 64) * HW + (size_t)hwt * 64;
  int tid = threadIdx.x;
  int cq = tid >> 4, hw0 = (tid & 15) * 4;
  #pragma unroll
  for (int p = 0; p < 4; ++p){
    int c = p * 16 + cq;
    const float* sp = src + (size_t)c * HW + hw0;
    float4 v = *reinterpret_cast<const float4*>(sp);
    T[c][hw0] = v.x; T[c][hw0+1] = v.y; T[c][hw0+2] = v.z; T[c][hw0+3] = v.w;
  }
  __syncthreads();
  unsigned short* dst = Ft + (tbase + (size_t)bat * HW + (size_t)hwt * 64) * 256 + ct * 64;
  #pragma unroll
  for (int p = 0; p < 2; ++p){
    int id = p * 256 + tid;
    int t = id >> 3, c0 = (id & 7) * 8;
    u16x8 o;
    #pragma unroll
    for (int j = 0; j < 8; ++j) o[j] = f2bf(T[c0 + j][t]);
    *reinterpret_cast<u16x8*>(dst + (size_t)t * 256 + c0) = o;
  }
}

// ---- transpose back: Gt[token][c] bf16 -> fp32 out [C,HW], ALL 4 batches ----
__global__ __launch_bounds__(256, 2) void untrans_kernel(
    const unsigned short* __restrict__ Gt, float* __restrict__ outb)
{
  __shared__ float T[64][65];
  int bid = blockIdx.x;
  int r; int Hl; size_t tbase, ooff;
  if (bid < 4096){ r = bid;        Hl = 128; tbase = 0;     ooff = 0; }
  else if (bid < 5120){ r = bid - 4096; Hl = 64; tbase = 65536; ooff = 16777216; }
  else if (bid < 5376){ r = bid - 5120; Hl = 32; tbase = 81920; ooff = 20971520; }
  else { r = bid - 5376; Hl = 16; tbase = 86016; ooff = 22020096; }
  size_t HW = (size_t)Hl * Hl;
  int hw64 = (int)(HW >> 6);
  int bat = r / (4 * hw64);
  int r2 = r - bat * 4 * hw64;
  int ct = r2 / hw64, hwt = r2 - ct * hw64;

  const unsigned short* src = Gt + (tbase + (size_t)bat * HW + (size_t)hwt * 64) * 256 + ct * 64;
  int tid = threadIdx.x;
  #pragma unroll
  for (int p = 0; p < 2; ++p){
    int id = p * 256 + tid;
    int t = id >> 3, c0 = (id & 7) * 8;
    u16x8 v = *reinterpret_cast<const u16x8*>(src + (size_t)t * 256 + c0);
    #pragma unroll
    for (int j = 0; j < 8; ++j) T[t][c0 + j] = bf2f(v[j]);
  }
  __syncthreads();
  float* dst = outb + ooff + (size_t)bat * HW * 256 + (size_t)(ct * 64) * HW + (size_t)hwt * 64;
  int cq = tid >> 4, hw0 = (tid & 15) * 4;
  #pragma unroll
  for (int p = 0; p < 4; ++p){
    int c = p * 16 + cq;
    float4 v;
    v.x = T[hw0][c]; v.y = T[hw0+1][c]; v.z = T[hw0+2][c]; v.w = T[hw0+3][c];
    *reinterpret_cast<float4*>(dst + (size_t)c * HW + hw0) = v;
  }
}

// ---- window geometry --------------------------------------------------------
struct WinGeo { int H, W, b, lvl; size_t HW, winoff, tbase, ooff; };

__device__ __forceinline__ WinGeo decode_win(int win){
  WinGeo g; int wloc;
  if (win < 512){ g.lvl = 0; wloc = win;      g.H = 128; g.tbase = 0;     g.ooff = 0; }
  else if (win < 640){ g.lvl = 1; wloc = win - 512; g.H = 64; g.tbase = 65536; g.ooff = 16777216; }
  else if (win < 672){ g.lvl = 2; wloc = win - 640; g.H = 32; g.tbase = 81920; g.ooff = 20971520; }
  else { g.lvl = 3; wloc = win - 672; g.H = 16; g.tbase = 86016; g.ooff = 22020096; }
  g.W = g.H; g.HW = (size_t)g.H * g.W;
  int nww = g.H >> 3, npb = nww * nww;
  g.b = wloc / npb;
  int r = wloc - g.b * npb;
  int wh = r / nww, ww = r - wh * nww;
  g.winoff = (size_t)(wh * 8) * g.W + (size_t)(ww * 8);
  return g;
}

// ---- v8: fully fused per-window kernel --------------------------------------
__global__ __launch_bounds__(256, 2) void swin_win(
    const unsigned short* __restrict__ Ft, const unsigned short* __restrict__ Gtin,
    const unsigned short* __restrict__ wball,
    unsigned short* __restrict__ Gt, int phase)
{
  __shared__ alignas(16) unsigned short A[64*264];   // K -> P -> O -> out
  __shared__ alignas(16) unsigned short B[256*72];   // Q ([64][264] view) -> V^T
  int win = blockIdx.x;
  WinGeo g = decode_win(win);
  int tid = threadIdx.x;
  int w = tid >> 6, l = tid & 63, l15 = l & 15, l4 = l >> 4, wd = w * 64;
  int h = w >> 1, tc = w & 1;

  int batx = (phase == 0) ? g.b : g.b + 2;
  const unsigned short* Sx = Ft + (g.tbase + (size_t)batx * g.HW) * 256;
  const unsigned short* Sy = (phase == 0)
      ? Ft + (g.tbase + (size_t)(g.b + 2) * g.HW) * 256
      : Gtin + (g.tbase + (size_t)g.b * g.HW) * 256;
  unsigned short* Gout = Gt + (g.tbase + (size_t)batx * g.HW) * 256;

  size_t rowo[4];
  #pragma unroll
  for (int ni = 0; ni < 4; ++ni){
    int t = ni * 16 + l15;
    rowo[ni] = ((size_t)g.winoff + (size_t)(t >> 3) * g.W + (t & 7)) * 256;
  }
  const unsigned short* Wbase = wball + ((size_t)(phase * 16 + g.lvl * 4) << 16);
  const unsigned short* Wq = Wbase;
  const unsigned short* Wk = Wbase + 65536;
  const unsigned short* Wv = Wbase + 131072;
  const unsigned short* Wo = Wbase + 196608;

  // ---- K & V GEMMs interleaved, shared Sy fragments (Sy read ONCE) ----
  f32x4 av[4][4];
  {
    f32x4 ak[4][4];
    #pragma unroll
    for (int i = 0; i < 4; ++i)
      #pragma unroll
      for (int j = 0; j < 4; ++j){ ak[i][j] = f32x4{0.f,0.f,0.f,0.f}; av[i][j] = f32x4{0.f,0.f,0.f,0.f}; }
    #pragma unroll
    for (int ks = 0; ks < 8; ++ks){
      int k0 = ks * 32 + l4 * 8;
      bf16x8 tf[4], kf[4], vf[4];
      #pragma unroll
      for (int i = 0; i < 4; ++i){
        tf[i] = *reinterpret_cast<const bf16x8*>(Sy + rowo[i] + k0);
        kf[i] = *reinterpret_cast<const bf16x8*>(Wk + (size_t)((wd + i*16 + l15) * 256 + k0));
        vf[i] = *reinterpret_cast<const bf16x8*>(Wv + (size_t)((wd + i*16 + l15) * 256 + k0));
      }
      __builtin_amdgcn_s_setprio(1);
      #pragma unroll
      for (int mi = 0; mi < 4; ++mi)
        #pragma unroll
        for (int ni = 0; ni < 4; ++ni){
          ak[mi][ni] = MFMA16(kf[mi], tf[ni], ak[mi][ni], 0, 0, 0);
          av[mi][ni] = MFMA16(tf[mi], vf[ni], av[mi][ni], 0, 0, 0);
        }
      __builtin_amdgcn_s_setprio(0);
    }
    // K[u][d] -> A
    #pragma unroll
    for (int mi = 0; mi < 4; ++mi){
      int d0 = wd + mi*16 + l4*4;
      #pragma unroll
      for (int ni = 0; ni < 4; ++ni)
        store_bf4(&A[(ni*16 + l15) * 264 + d0], ak[mi][ni]);
    }
  }
  // av stays live in registers until after S.

  // ---- Q GEMM -> B ([64][264] view) ----
  {
    f32x4 aq[4][4];
    #pragma unroll
    for (int i = 0; i < 4; ++i)
      #pragma unroll
      for (int j = 0; j < 4; ++j) aq[i][j] = f32x4{0.f,0.f,0.f,0.f};
    #pragma unroll
    for (int ks = 0; ks < 8; ++ks){
      int k0 = ks * 32 + l4 * 8;
      bf16x8 tf[4], wf[4];
      #pragma unroll
      for (int i = 0; i < 4; ++i){
        tf[i] = *reinterpret_cast<const bf16x8*>(Sx + rowo[i] + k0);
        wf[i] = *reinterpret_cast<const bf16x8*>(Wq + (size_t)((wd + i*16 + l15) * 256 + k0));
      }
      __builtin_amdgcn_s_setprio(1);
      #pragma unroll
      for (int mi = 0; mi < 4; ++mi)
        #pragma unroll
        for (int ni = 0; ni < 4; ++ni)
          aq[mi][ni] = MFMA16(wf[mi], tf[ni], aq[mi][ni], 0, 0, 0);
      __builtin_amdgcn_s_setprio(0);
    }
    #pragma unroll
    for (int mi = 0; mi < 4; ++mi){
      int d0 = wd + mi*16 + l4*4;
      #pragma unroll
      for (int ni = 0; ni < 4; ++ni)
        store_bf4(&B[(ni*16 + l15) * 264 + d0], aq[mi][ni]);
    }
  }
  __syncthreads();   // sync0: K(A), Q(B) visible

  // ---- S^T[u][t] per head from LDS K,Q ----
  f32x4 s[4][2];
  #pragma unroll
  for (int i = 0; i < 4; ++i){ s[i][0] = f32x4{0.f,0.f,0.f,0.f}; s[i][1] = f32x4{0.f,0.f,0.f,0.f}; }
  #pragma unroll
  for (int ks = 0; ks < 4; ++ks){
    int k0 = h * 128 + ks * 32 + l4 * 8;
    bf16x8 a[4], bb[2];
    #pragma unroll
    for (int mi = 0; mi < 4; ++mi)
      a[mi] = *reinterpret_cast<const bf16x8*>(&A[(mi*16 + l15) * 264 + k0]);
    #pragma unroll
    for (int ni = 0; ni < 2; ++ni)
      bb[ni] = *reinterpret_cast<const bf16x8*>(&B[(tc*32 + ni*16 + l15) * 264 + k0]);
    __builtin_amdgcn_s_setprio(1);
    #pragma unroll
    for (int mi = 0; mi < 4; ++mi)
      #pragma unroll
      for (int ni = 0; ni < 2; ++ni)
        s[mi][ni] = MFMA16(a[mi], bb[ni], s[mi][ni], 0, 0, 0);
    __builtin_amdgcn_s_setprio(0);
  }
  __syncthreads();   // sync1: K,Q reads done; A free for P, B free for V^T

  // ---- V^T (from registers) -> B ----
  #pragma unroll
  for (int mi = 0; mi < 4; ++mi){
    int u0 = mi*16 + l4*4;
    #pragma unroll
    for (int ni = 0; ni < 4; ++ni)
      store_bf4(&B[(wd + ni*16 + l15) * 72 + u0], av[mi][ni]);
  }

  // ---- softmax over u (per column t), P -> A ----
  const float SCL = 0.08838834764831845f;   // 1/sqrt(128)
  #pragma unroll
  for (int ni = 0; ni < 2; ++ni){
    float m = s[0][ni][0];
    #pragma unroll
    for (int mi = 0; mi < 4; ++mi)
      #pragma unroll
      for (int reg = 0; reg < 4; ++reg) m = fmaxf(m, s[mi][ni][reg]);
    m = fmaxf(m, __shfl_xor(m, 16));
    m = fmaxf(m, __shfl_xor(m, 32));
    float sum = 0.f;
    #pragma unroll
    for (int mi = 0; mi < 4; ++mi)
      #pragma unroll
      for (int reg = 0; reg < 4; ++reg){
        float e = __expf((s[mi][ni][reg] - m) * SCL);
        s[mi][ni][reg] = e; sum += e;
      }
    sum += __shfl_xor(sum, 16);
    sum += __shfl_xor(sum, 32);
    float rs = 1.0f / sum;
    int t = tc*32 + ni*16 + l15;
    #pragma unroll
    for (int mi = 0; mi < 4; ++mi){
      f32x4 pv;
      #pragma unroll
      for (int reg = 0; reg < 4; ++reg) pv[reg] = s[mi][ni][reg] * rs;
      store_bf4(&A[h * 4608 + t * 72 + mi*16 + l4*4], pv);
    }
  }
  __syncthreads();   // sync2: P(A), V^T(B) visible

  // ---- O^T[c][t] = V^T * P^T (both from LDS) ----
  f32x4 acc[4][4];
  #pragma unroll
  for (int i = 0; i < 4; ++i)
    #pragma unroll
    for (int j = 0; j < 4; ++j) acc[i][j] = f32x4{0.f,0.f,0.f,0.f};
  #pragma unroll
  for (int ks = 0; ks < 2; ++ks){
    int k0 = ks * 32 + l4 * 8;
    bf16x8 a[4], bb[4];
    #pragma unroll
    for (int mi = 0; mi < 4; ++mi)
      a[mi] = *reinterpret_cast<const bf16x8*>(&B[(wd + mi*16 + l15) * 72 + k0]);
    #pragma unroll
    for (int ni = 0; ni < 4; ++ni)
      bb[ni] = *reinterpret_cast<const bf16x8*>(&A[h * 4608 + (ni*16 + l15) * 72 + k0]);
    __builtin_amdgcn_s_setprio(1);
    #pragma unroll
    for (int mi = 0; mi < 4; ++mi)
      #pragma unroll
      for (int ni = 0; ni < 4; ++ni)
        acc[mi][ni] = MFMA16(a[mi], bb[ni], acc[mi][ni], 0, 0, 0);
    __builtin_amdgcn_s_setprio(0);
  }
  __syncthreads();   // sync3: P reads done; A free for O
  #pragma unroll
  for (int mi = 0; mi < 4; ++mi){
    int c0 = wd + mi*16 + l4*4;
    #pragma unroll
    for (int ni = 0; ni < 4; ++ni)
      store_bf4(&A[(ni*16 + l15) * 264 + c0], acc[mi][ni]);
  }
  __syncthreads();   // sync4: O(A) visible

  // ---- out^T = Wo * o^T ----
  #pragma unroll
  for (int i = 0; i < 4; ++i)
    #pragma unroll
    for (int j = 0; j < 4; ++j) acc[i][j] = f32x4{0.f,0.f,0.f,0.f};
  #pragma unroll
  for (int ks = 0; ks < 8; ++ks){
    int k0 = ks * 32 + l4 * 8;
    bf16x8 a[4], bb[4];
    #pragma unroll
    for (int mi = 0; mi < 4; ++mi)
      a[mi] = *reinterpret_cast<const bf16x8*>(Wo + (size_t)((wd + mi*16 + l15) * 256 + k0));
    #pragma unroll
    for (int ni = 0; ni < 4; ++ni)
      bb[ni] = *reinterpret_cast<const bf16x8*>(&A[(ni*16 + l15) * 264 + k0]);
    __builtin_amdgcn_s_setprio(1);
    #pragma unroll
    for (int mi = 0; mi < 4; ++mi)
      #pragma unroll
      for (int ni = 0; ni < 4; ++ni)
        acc[mi][ni] = MFMA16(a[mi], bb[ni], acc[mi][ni], 0, 0, 0);
    __builtin_amdgcn_s_setprio(0);
  }
  __syncthreads();   // sync5: O reads done; A free for out tile
  #pragma unroll
  for (int mi = 0; mi < 4; ++mi){
    int c0 = wd + mi*16 + l4*4;
    #pragma unroll
    for (int ni = 0; ni < 4; ++ni)
      store_bf4(&A[(ni*16 + l15) * 264 + c0], acc[mi][ni]);
  }
  __syncthreads();   // sync6: out(A) visible

  // ---- fused flush: out + residual, relu, 16B coalesced -> Gt ----
  #pragma unroll
  for (int p = 0; p < 8; ++p){
    int id = p * 256 + tid;
    int t = id >> 5, c = (id & 31) * 8;
    size_t ro = ((size_t)g.winoff + (size_t)(t >> 3) * g.W + (t & 7)) * 256 + c;
    u16x8 ov = *reinterpret_cast<const u16x8*>(&A[t * 264 + c]);
    u16x8 rv = *reinterpret_cast<const u16x8*>(Sx + ro);
    u16x8 o;
    #pragma unroll
    for (int j = 0; j < 8; ++j)
      o[j] = f2bf(fmaxf(bf2f(ov[j]) + bf2f(rv[j]), 0.f));
    *reinterpret_cast<u16x8*>(Gout + ro) = o;
  }
}

// ======================= round-1 fused fallback ==============================
__global__ __launch_bounds__(256, 1) void swin_phase(
    const float* __restrict__ g0, const float* __restrict__ g1,
    const float* __restrict__ g2, const float* __restrict__ g3,
    const unsigned short* __restrict__ wball,
    float* __restrict__ outb, int phase)
{
  __shared__ alignas(16) unsigned short R0[64*264];
  __shared__ alignas(16) unsigned short R1[64*264];
  __shared__ alignas(16) unsigned short R2[256*72];
  __shared__ alignas(16) unsigned short R3[64*264];

  int bid = blockIdx.x;
  WinGeo g = decode_win(bid);
  const float* feat = (g.lvl == 0) ? g0 : (g.lvl == 1) ? g1 : (g.lvl == 2) ? g2 : g3;
  size_t CHW = g.HW * 256;

  const float* xsrc; const float* ysrc; float* outp;
  if (phase == 0){
    xsrc = feat + (size_t)g.b * CHW + g.winoff;
    ysrc = feat + (size_t)(g.b + 2) * CHW + g.winoff;
    outp = outb + g.ooff + (size_t)g.b * CHW + g.winoff;
  } else {
    xsrc = feat + (size_t)(g.b + 2) * CHW + g.winoff;
    ysrc = outb + g.ooff + (size_t)g.b * CHW + g.winoff;
    outp = outb + g.ooff + (size_t)(g.b + 2) * CHW + g.winoff;
  }
  const unsigned short* Wq = wball + ((size_t)(phase * 16 + g.lvl * 4) << 16);
  const unsigned short* Wk = Wq + 65536;
  const unsigned short* Wv = Wq + 2 * 65536;
  const unsigned short* Wo = Wq + 3 * 65536;

  int tid = threadIdx.x;
  int w = tid >> 6, l = tid & 63, l15 = l & 15, l4 = l >> 4, wd = w * 64;
  int hi0 = l >> 3, wi0 = l & 7;

  {
    const float* p0 = ysrc + (size_t)hi0 * g.W + wi0;
    #pragma unroll
    for (int oc = 0; oc < 8; ++oc){
      int c0 = (oc * 4 + w) * 8;
      const float* p = p0 + (size_t)c0 * g.HW;
      u16x8 uv;
      #pragma unroll
      for (int j = 0; j < 8; ++j) uv[j] = f2bf(p[(size_t)j * g.HW]);
      *reinterpret_cast<u16x8*>(&R0[l * 264 + c0]) = uv;
    }
  }
  __syncthreads();
  {
    f32x4 acc[4][4];
    #pragma unroll
    for (int i = 0; i < 4; ++i)
      #pragma unroll
      for (int j = 0; j < 4; ++j) acc[i][j] = f32x4{0.f,0.f,0.f,0.f};
    #pragma unroll
    for (int ks = 0; ks < 8; ++ks){
      int k0 = ks * 32 + l4 * 8;
      bf16x8 a[4], bb[4];
      #pragma unroll
      for (int mi = 0; mi < 4; ++mi)
        a[mi] = *reinterpret_cast<const bf16x8*>(Wk + (size_t)((wd + mi*16 + l15) * 256 + k0));
      #pragma unroll
      for (int ni = 0; ni < 4; ++ni)
        bb[ni] = *reinterpret_cast<const bf16x8*>(&R0[(ni*16 + l15) * 264 + k0]);
      #pragma unroll
      for (int mi = 0; mi < 4; ++mi)
        #pragma unroll
        for (int ni = 0; ni < 4; ++ni)
          acc[mi][ni] = MFMA16(a[mi], bb[ni], acc[mi][ni], 0, 0, 0);
    }
    #pragma unroll
    for (int mi = 0; mi < 4; ++mi){
      int d0 = wd + mi*16 + l4*4;
      #pragma unroll
      for (int ni = 0; ni < 4; ++ni)
        store_bf4(&R1[(ni*16 + l15) * 264 + d0], acc[mi][ni]);
    }
  }
  {
    f32x4 acc[4][4];
    #pragma unroll
    for (int i = 0; i < 4; ++i)
      #pragma unroll
      for (int j = 0; j < 4; ++j) acc[i][j] = f32x4{0.f,0.f,0.f,0.f};
    #pragma unroll
    for (int ks = 0; ks < 8; ++ks){
      int k0 = ks * 32 + l4 * 8;
      bf16x8 a[4], bb[4];
      #pragma unroll
      for (int mi = 0; mi < 4; ++mi)
        a[mi] = *reinterpret_cast<const bf16x8*>(&R0[(mi*16 + l15) * 264 + k0]);
      #pragma unroll
      for (int ni = 0; ni < 4; ++ni)
        bb[ni] = *reinterpret_cast<const bf16x8*>(Wv + (size_t)((wd + ni*16 + l15) * 256 + k0));
      #pragma unroll
      for (int mi = 0; mi < 4; ++mi)
        #pragma unroll
        for (int ni = 0; ni < 4; ++ni)
          acc[mi][ni] = MFMA16(a[mi], bb[ni], acc[mi][ni], 0, 0, 0);
    }
    #pragma unroll
    for (int mi = 0; mi < 4; ++mi){
      int u0 = mi*16 + l4*4;
      #pragma unroll
      for (int ni = 0; ni < 4; ++ni)
        store_bf4(&R2[(wd + ni*16 + l15) * 72 + u0], acc[mi][ni]);
    }
  }
  __syncthreads();
  {
    const float* p0 = xsrc + (size_t)hi0 * g.W + wi0;
    #pragma unroll
    for (int oc = 0; oc < 8; ++oc){
      int c0 = (oc * 4 + w) * 8;
      const float* p = p0 + (size_t)c0 * g.HW;
      u16x8 uv;
      #pragma unroll
      for (int j = 0; j < 8; ++j) uv[j] = f2bf(p[(size_t)j * g.HW]);
      *reinterpret_cast<u16x8*>(&R0[l * 264 + c0]) = uv;
    }
  }
  __syncthreads();
  {
    f32x4 acc[4][4];
    #pragma unroll
    for (int i = 0; i < 4; ++i)
      #pragma unroll
      for (int j = 0; j < 4; ++j) acc[i][j] = f32x4{0.f,0.f,0.f,0.f};
    #pragma unroll
    for (int ks = 0; ks < 8; ++ks){
      int k0 = ks * 32 + l4 * 8;
      bf16x8 a[4], bb[4];
      #pragma unroll
      for (int mi = 0; mi < 4; ++mi)
        a[mi] = *reinterpret_cast<const bf16x8*>(Wq + (size_t)((wd + mi*16 + l15) * 256 + k0));
      #pragma unroll
      for (int ni = 0; ni < 4; ++ni)
        bb[ni] = *reinterpret_cast<const bf16x8*>(&R0[(ni*16 + l15) * 264 + k0]);
      #pragma unroll
      for (int mi = 0; mi < 4; ++mi)
        #pragma unroll
        for (int ni = 0; ni < 4; ++ni)
          acc[mi][ni] = MFMA16(a[mi], bb[ni], acc[mi][ni], 0, 0, 0);
    }
    #pragma unroll
    for (int mi = 0; mi < 4; ++mi){
      int d0 = wd + mi*16 + l4*4;
      #pragma unroll
      for (int ni = 0; ni < 4; ++ni)
        store_bf4(&R3[(ni*16 + l15) * 264 + d0], acc[mi][ni]);
    }
  }
  __syncthreads();

  int h = w >> 1, tc = w & 1;
  {
    f32x4 s[4][2];
    #pragma unroll
    for (int i = 0; i < 4; ++i){ s[i][0] = f32x4{0.f,0.f,0.f,0.f}; s[i][1] = f32x4{0.f,0.f,0.f,0.f}; }
    #pragma unroll
    for (int ks = 0; ks < 4; ++ks){
      int k0 = h * 128 + ks * 32 + l4 * 8;
      bf16x8 a[4], bb[2];
      #pragma unroll
      for (int mi = 0; mi < 4; ++mi)
        a[mi] = *reinterpret_cast<const bf16x8*>(&R1[(mi*16 + l15) * 264 + k0]);
      #pragma unroll
      for (int ni = 0; ni < 2; ++ni)
        bb[ni] = *reinterpret_cast<const bf16x8*>(&R3[(tc*32 + ni*16 + l15) * 264 + k0]);
      #pragma unroll
      for (int mi = 0; mi < 4; ++mi)
        #pragma unroll
        for (int ni = 0; ni < 2; ++ni)
          s[mi][ni] = MFMA16(a[mi], bb[ni], s[mi][ni], 0, 0, 0);
    }
    __syncthreads();
    const float SCL = 0.08838834764831845f;
    unsigned short* P = R1;
    #pragma unroll
    for (int ni = 0; ni < 2; ++ni){
      float m = s[0][ni][0];
      #pragma unroll
      for (int mi = 0; mi < 4; ++mi)
        #pragma unroll
        for (int reg = 0; reg < 4; ++reg) m = fmaxf(m, s[mi][ni][reg]);
      m = fmaxf(m, __shfl_xor(m, 16));
      m = fmaxf(m, __shfl_xor(m, 32));
      float sum = 0.f;
      #pragma unroll
      for (int mi = 0; mi < 4; ++mi)
        #pragma unroll
        for (int reg = 0; reg < 4; ++reg){
          float e = __expf((s[mi][ni][reg] - m) * SCL);
          s[mi][ni][reg] = e; sum += e;
        }
      sum += __shfl_xor(sum, 16);
      sum += __shfl_xor(sum, 32);
      float rs = 1.0f / sum;
      int t = tc*32 + ni*16 + l15;
      #pragma unroll
      for (int mi = 0; mi < 4; ++mi){
        f32x4 pv;
        #pragma unroll
        for (int reg = 0; reg < 4; ++reg) pv[reg] = s[mi][ni][reg] * rs;
        store_bf4(&P[h * 4608 + t * 72 + mi*16 + l4*4], pv);
      }
    }
  }
  __syncthreads();
  {
    int wdh = h * 128 + tc * 64;
    f32x4 acc[4][4];
    #pragma unroll
    for (int i = 0; i < 4; ++i)
      #pragma unroll
      for (int j = 0; j < 4; ++j) acc[i][j] = f32x4{0.f,0.f,0.f,0.f};
    const unsigned short* P = R1;
    #pragma unroll
    for (int ks = 0; ks < 2; ++ks){
      int k0 = ks * 32 + l4 * 8;
      bf16x8 a[4], bb[4];
      #pragma unroll
      for (int mi = 0; mi < 4; ++mi)
        a[mi] = *reinterpret_cast<const bf16x8*>(&R2[(wdh + mi*16 + l15) * 72 + k0]);
      #pragma unroll
      for (int ni = 0; ni < 4; ++ni)
        bb[ni] = *reinterpret_cast<const bf16x8*>(&P[h * 4608 + (ni*16 + l15) * 72 + k0]);
      #pragma unroll
      for (int mi = 0; mi < 4; ++mi)
        #pragma unroll
        for (int ni = 0; ni < 4; ++ni)
          acc[mi][ni] = MFMA16(a[mi], bb[ni], acc[mi][ni], 0, 0, 0);
    }
    #pragma unroll
    for (int mi = 0; mi < 4; ++mi){
      int c0 = wdh + mi*16 + l4*4;
      #pragma unroll
      for (int ni = 0; ni < 4; ++ni)
        store_bf4(&R0[(ni*16 + l15) * 264 + c0], acc[mi][ni]);
    }
  }
  __syncthreads();
  {
    f32x4 acc[4][4];
    #pragma unroll
    for (int i = 0; i < 4; ++i)
      #pragma unroll
      for (int j = 0; j < 4; ++j) acc[i][j] = f32x4{0.f,0.f,0.f,0.f};
    #pragma unroll
    for (int ks = 0; ks < 8; ++ks){
      int k0 = ks * 32 + l4 * 8;
      bf16x8 a[4], bb[4];
      #pragma unroll
      for (int mi = 0; mi < 4; ++mi)
        a[mi] = *reinterpret_cast<const bf16x8*>(Wo + (size_t)((wd + mi*16 + l15) * 256 + k0));
      #pragma unroll
      for (int ni = 0; ni < 4; ++ni)
        bb[ni] = *reinterpret_cast<const bf16x8*>(&R0[(ni*16 + l15) * 264 + k0]);
      #pragma unroll
      for (int mi = 0; mi < 4; ++mi)
        #pragma unroll
        for (int ni = 0; ni < 4; ++ni)
          acc[mi][ni] = MFMA16(a[mi], bb[ni], acc[mi][ni], 0, 0, 0);
    }
    #pragma unroll
    for (int mi = 0; mi < 4; ++mi){
      #pragma unroll
      for (int ni = 0; ni < 4; ++ni){
        int t = ni*16 + l15, thi = t >> 3, twi = t & 7;
        size_t base = (size_t)(wd + mi*16 + l4*4) * g.HW + (size_t)thi * g.W + twi;
        #pragma unroll
        for (int reg = 0; reg < 4; ++reg){
          float res = xsrc[base + (size_t)reg * g.HW];
          float v = acc[mi][ni][reg] + res;
          outp[base + (size_t)reg * g.HW] = fmaxf(v, 0.f);
        }
      }
    }
  }
}

extern "C" void kernel_launch(void* const* d_in, const int* in_sizes, int n_in,
                              void* d_out, int out_size, void* d_ws, size_t ws_size,
                              hipStream_t stream) {
  (void)in_sizes; (void)n_in; (void)out_size;
  const float* f0 = (const float*)d_in[0];
  const float* f1 = (const float*)d_in[1];
  const float* f2 = (const float*)d_in[2];
  const float* f3 = (const float*)d_in[3];
  const float* w1 = (const float*)d_in[4];
  const float* w2 = (const float*)d_in[5];
  float* out = (float*)d_out;

  unsigned short* wbf = (unsigned short*)d_ws;
  const size_t WBF_B = 4194304;       // 2*16*65536 bf16
  const size_t FT_B  = 44564480;      // 87040 tokens * 256 * 2B
  const size_t need  = WBF_B + 2 * FT_B;   // 93,323,264

  wcvt_kernel<<<2048, 256, 0, stream>>>(w1, w2, wbf);

  if (ws_size >= need){
    char* base = (char*)d_ws + WBF_B;
    unsigned short* Ft = (unsigned short*)(base);
    unsigned short* Gt = (unsigned short*)(base + FT_B);

    xpose_kernel<<<5440, 256, 0, stream>>>(f0, f1, f2, f3, Ft);
    for (int phase = 0; phase < 2; ++phase)
      swin_win<<<680, 256, 0, stream>>>(Ft, Gt, wbf, Gt, phase);
    untrans_kernel<<<5440, 256, 0, stream>>>(Gt, out);
  } else {
    swin_phase<<<680, 256, 0, stream>>>(f0, f1, f2, f3, wbf, out, 0);
    swin_phase<<<680, 256, 0, stream>>>(f0, f1, f2, f3, wbf, out, 1);
  }
}